// Round 2
// baseline (454.010 us; speedup 1.0000x reference)
//
#include <hip/hip_runtime.h>
#include <hip/hip_bf16.h>
#include <math.h>

#define D 128

__device__ __forceinline__ float gelu_exact(float x) {
    return 0.5f * x * (1.0f + erff(x * 0.70710678118654752440f));
}
__device__ __forceinline__ float elu1(float x) {
    return x > 0.f ? x : expm1f(x);
}

// ---------------------------------------------------------------------------
// Detect whether edge_index buffer is int64 (high dwords all zero) or int32.
__global__ void detect64_kernel(const int* __restrict__ p, int* __restrict__ flag, int npairs) {
    __shared__ int any;
    if (threadIdx.x == 0) any = 0;
    __syncthreads();
    for (int i = threadIdx.x; i < npairs; i += blockDim.x) {
        if (p[2 * i + 1] != 0) any = 1;   // benign race
    }
    __syncthreads();
    if (threadIdx.x == 0) flag[0] = any ? 0 : 1;
}

// ---------------------------------------------------------------------------
__global__ void count_deg_kernel(const int* __restrict__ ep, const int* __restrict__ flag,
                                 int* __restrict__ deg, int E) {
    int e = blockIdx.x * blockDim.x + threadIdx.x;
    if (e >= E) return;
    int mode = flag[0];
    int c = mode ? ep[2 * (E + e)] : ep[E + e];
    atomicAdd(&deg[c], 1);
}

// ---------------------------------------------------------------------------
// Exclusive scan of deg[0..n) -> rowptr[0..n]. Single block, 1024 threads.
__global__ __launch_bounds__(1024) void scan_exclusive_kernel(const int* __restrict__ deg,
                                                              int* __restrict__ rowptr, int n) {
    __shared__ int wsum[16];
    __shared__ int carry_s;
    const int tid = threadIdx.x;
    const int lane = tid & 63;
    const int wv = tid >> 6;
    if (tid == 0) carry_s = 0;
    __syncthreads();
    for (int base = 0; base < n; base += 1024) {
        int idx = base + tid;
        int v = (idx < n) ? deg[idx] : 0;
        int s = v;
        #pragma unroll
        for (int off = 1; off < 64; off <<= 1) {
            int t = __shfl_up(s, off);
            if (lane >= off) s += t;
        }
        if (lane == 63) wsum[wv] = s;
        int c0 = carry_s;
        __syncthreads();
        if (wv == 0) {
            int ws = (lane < 16) ? wsum[lane] : 0;
            #pragma unroll
            for (int off = 1; off < 16; off <<= 1) {
                int t = __shfl_up(ws, off);
                if (lane >= off) ws += t;
            }
            if (lane < 16) wsum[lane] = ws;
        }
        __syncthreads();
        int woff = (wv == 0) ? 0 : wsum[wv - 1];
        if (idx < n) rowptr[idx] = c0 + woff + s - v;
        int total = wsum[15];
        __syncthreads();
        if (tid == 0) carry_s = c0 + total;
        __syncthreads();
    }
    if (threadIdx.x == 0) rowptr[n] = carry_s;
}

// ---------------------------------------------------------------------------
__global__ void dinv_kernel(const int* __restrict__ deg, float* __restrict__ dinv, int n) {
    int i = blockIdx.x * blockDim.x + threadIdx.x;
    if (i >= n) return;
    dinv[i] = 1.0f / sqrtf((float)(deg[i] + 1));   // +1 self loop
}

// ---------------------------------------------------------------------------
__global__ void fill_csr_kernel(const int* __restrict__ ep, const int* __restrict__ flag,
                                const int* __restrict__ rowptr, int* __restrict__ cursor,
                                int* __restrict__ csr, int E) {
    int e = blockIdx.x * blockDim.x + threadIdx.x;
    if (e >= E) return;
    int mode = flag[0];
    int r = mode ? ep[2 * e] : ep[e];
    int c = mode ? ep[2 * (E + e)] : ep[E + e];
    int pos = atomicAdd(&cursor[c], 1);
    csr[rowptr[c] + pos] = r;
}

// ---------------------------------------------------------------------------
// Transpose the three 128x128 weights into WT (k-major).
__global__ void transpose3_kernel(const float* __restrict__ W1, const float* __restrict__ Wt2,
                                  const float* __restrict__ W2, float* __restrict__ WT) {
    int idx = blockIdx.x * blockDim.x + threadIdx.x;   // 0 .. 3*16384
    int m = idx >> 14;
    int flat = idx & 16383;
    int j = flat >> 7, k = flat & 127;
    const float* src = (m == 0) ? W1 : ((m == 1) ? Wt2 : W2);
    WT[m * 16384 + k * 128 + j] = src[flat];
}

// ---------------------------------------------------------------------------
// GEMM v2: out[r][j] = sum_k A[r][k] * WT[k][j]
//   128 rows/block, 256 threads (16x16), 8x8 micro-kernel.
//   Only W staged in LDS (66 KB -> 2 blocks/CU). A read direct from global:
//   all 16 lanes sharing a (r,k) fragment hit the SAME address in the SAME
//   instruction -> broadcast, no redundant traffic.
// MODE 0: A = Ain; epilogue: out = dinv[r] * acc
// MODE 1: A[r][k] = gelu(r * wt1[k] + bt1[k]); epilogue: out = acc + bias[j] + bias2[j]
template <int MODE>
__global__ __launch_bounds__(256) void gemm128_v2(
    const float* __restrict__ Ain,
    const float* __restrict__ wt1, const float* __restrict__ bt1,
    const float* __restrict__ WT,
    const float* __restrict__ bias, const float* __restrict__ bias2,
    const float* __restrict__ dinv,
    float* __restrict__ out, int n) {
    __shared__ float Wsh[128][132];
    const int tid = threadIdx.x;
    const int r0 = blockIdx.x * 128;

    // stage WT -> Wsh
    #pragma unroll
    for (int rep = 0; rep < 16; ++rep) {
        int flat = (rep * 256 + tid) * 4;
        int k = flat >> 7, j = flat & 127;
        *(float4*)&Wsh[k][j] = *(const float4*)(WT + flat);
    }
    __syncthreads();

    const int tx = tid & 15, ty = tid >> 4;
    const int rbase = r0 + ty * 8;

    float acc[8][8];
    #pragma unroll
    for (int i = 0; i < 8; ++i)
        #pragma unroll
        for (int j = 0; j < 8; ++j) acc[i][j] = 0.f;

    #pragma unroll 2
    for (int k0 = 0; k0 < 128; k0 += 4) {
        float4 a[8];
        if (MODE == 1) {
            float4 w1 = *(const float4*)(wt1 + k0);
            float4 bv = *(const float4*)(bt1 + k0);
            #pragma unroll
            for (int i = 0; i < 8; ++i) {
                float tv = (float)(rbase + i);
                a[i].x = gelu_exact(fmaf(tv, w1.x, bv.x));
                a[i].y = gelu_exact(fmaf(tv, w1.y, bv.y));
                a[i].z = gelu_exact(fmaf(tv, w1.z, bv.z));
                a[i].w = gelu_exact(fmaf(tv, w1.w, bv.w));
            }
        } else {
            #pragma unroll
            for (int i = 0; i < 8; ++i) {
                int rr = rbase + i;
                a[i] = (rr < n) ? *(const float4*)(Ain + (size_t)rr * D + k0)
                                : make_float4(0.f, 0.f, 0.f, 0.f);
            }
        }
        float4 wv[4][2];
        #pragma unroll
        for (int kk = 0; kk < 4; ++kk) {
            wv[kk][0] = *(const float4*)&Wsh[k0 + kk][tx * 8];
            wv[kk][1] = *(const float4*)&Wsh[k0 + kk][tx * 8 + 4];
        }
        #pragma unroll
        for (int i = 0; i < 8; ++i) {
            float av[4] = {a[i].x, a[i].y, a[i].z, a[i].w};
            #pragma unroll
            for (int kk = 0; kk < 4; ++kk) {
                acc[i][0] = fmaf(av[kk], wv[kk][0].x, acc[i][0]);
                acc[i][1] = fmaf(av[kk], wv[kk][0].y, acc[i][1]);
                acc[i][2] = fmaf(av[kk], wv[kk][0].z, acc[i][2]);
                acc[i][3] = fmaf(av[kk], wv[kk][0].w, acc[i][3]);
                acc[i][4] = fmaf(av[kk], wv[kk][1].x, acc[i][4]);
                acc[i][5] = fmaf(av[kk], wv[kk][1].y, acc[i][5]);
                acc[i][6] = fmaf(av[kk], wv[kk][1].z, acc[i][6]);
                acc[i][7] = fmaf(av[kk], wv[kk][1].w, acc[i][7]);
            }
        }
    }

    float4 badd0 = make_float4(0.f, 0.f, 0.f, 0.f);
    float4 badd1 = make_float4(0.f, 0.f, 0.f, 0.f);
    if (MODE == 1) {
        float4 ba = *(const float4*)(bias + tx * 8);
        float4 bb = *(const float4*)(bias2 + tx * 8);
        badd0.x = ba.x + bb.x; badd0.y = ba.y + bb.y; badd0.z = ba.z + bb.z; badd0.w = ba.w + bb.w;
        ba = *(const float4*)(bias + tx * 8 + 4);
        bb = *(const float4*)(bias2 + tx * 8 + 4);
        badd1.x = ba.x + bb.x; badd1.y = ba.y + bb.y; badd1.z = ba.z + bb.z; badd1.w = ba.w + bb.w;
    }
    #pragma unroll
    for (int i = 0; i < 8; ++i) {
        int rr = rbase + i;
        if (rr < n) {
            float scale = (MODE == 0) ? dinv[rr] : 1.f;
            float4 o0, o1;
            o0.x = acc[i][0] * scale + badd0.x;
            o0.y = acc[i][1] * scale + badd0.y;
            o0.z = acc[i][2] * scale + badd0.z;
            o0.w = acc[i][3] * scale + badd0.w;
            o1.x = acc[i][4] * scale + badd1.x;
            o1.y = acc[i][5] * scale + badd1.y;
            o1.z = acc[i][6] * scale + badd1.z;
            o1.w = acc[i][7] * scale + badd1.w;
            *(float4*)(out + (size_t)rr * D + tx * 8) = o0;
            *(float4*)(out + (size_t)rr * D + tx * 8 + 4) = o1;
        }
    }
}

// ---------------------------------------------------------------------------
// Gather-aggregation over pre-scaled rows xw' (already multiplied by dinv[src]).
//   sum = xw'[i] + sum_{r in in(i)} xw'[r];  val = dinv[i]*sum
// EPI 0: dst[i] = val + bias            (final output + b2)
// EPI 1: dst[i] = elu(val + table[t[i]])  (h1 path, elu pre-applied for GEMM2)
template <int EPI>
__global__ __launch_bounds__(256) void gather_kernel(
    const float* __restrict__ xw, const float* __restrict__ dinv,
    const int* __restrict__ rowptr, const int* __restrict__ csr,
    const float* __restrict__ table, const int* __restrict__ tvec,
    const float* __restrict__ bias,
    float* __restrict__ dst, int n) {
    int wid = (blockIdx.x * 256 + threadIdx.x) >> 6;
    if (wid >= n) return;
    int lane = threadIdx.x & 63;
    const size_t lo = (size_t)lane * 2;

    // independent epilogue operands issued early
    float di = dinv[wid];
    float2 ep;
    if (EPI == 0) {
        ep = *(const float2*)(bias + lo);
    } else {
        int tv = tvec[wid];
        ep = *(const float2*)(table + (size_t)tv * D + lo);
    }

    float2 s = *(const float2*)(xw + (size_t)wid * D + lo);
    float sx = s.x, sy = s.y;
    int e = rowptr[wid], e1 = rowptr[wid + 1];
    for (; e + 4 <= e1; e += 4) {
        int r0 = csr[e], r1 = csr[e + 1], r2 = csr[e + 2], r3 = csr[e + 3];
        float2 u0 = *(const float2*)(xw + (size_t)r0 * D + lo);
        float2 u1 = *(const float2*)(xw + (size_t)r1 * D + lo);
        float2 u2 = *(const float2*)(xw + (size_t)r2 * D + lo);
        float2 u3 = *(const float2*)(xw + (size_t)r3 * D + lo);
        sx += (u0.x + u1.x) + (u2.x + u3.x);
        sy += (u0.y + u1.y) + (u2.y + u3.y);
    }
    if (e + 2 <= e1) {
        int r0 = csr[e], r1 = csr[e + 1];
        float2 u0 = *(const float2*)(xw + (size_t)r0 * D + lo);
        float2 u1 = *(const float2*)(xw + (size_t)r1 * D + lo);
        sx += u0.x + u1.x;
        sy += u0.y + u1.y;
        e += 2;
    }
    if (e < e1) {
        int r0 = csr[e];
        float2 u0 = *(const float2*)(xw + (size_t)r0 * D + lo);
        sx += u0.x;
        sy += u0.y;
    }

    float2 o;
    if (EPI == 0) {
        o.x = di * sx + ep.x;
        o.y = di * sy + ep.y;
    } else {
        o.x = elu1(di * sx + ep.x);
        o.y = elu1(di * sy + ep.y);
    }
    *(float2*)(dst + (size_t)wid * D + lo) = o;
}

// ---------------------------------------------------------------------------
extern "C" void kernel_launch(void* const* d_in, const int* in_sizes, int n_in,
                              void* d_out, int out_size, void* d_ws, size_t ws_size,
                              hipStream_t stream) {
    const float* z   = (const float*)d_in[0];
    const int*   ep  = (const int*)d_in[1];
    const int*   t   = (const int*)d_in[2];
    const float* Wt1 = (const float*)d_in[3];
    const float* bt1 = (const float*)d_in[4];
    const float* Wt2 = (const float*)d_in[5];
    const float* bt2 = (const float*)d_in[6];
    const float* W1  = (const float*)d_in[7];
    const float* b1  = (const float*)d_in[8];
    const float* W2  = (const float*)d_in[9];
    const float* b2  = (const float*)d_in[10];
    float* out = (float*)d_out;

    const int N = in_sizes[0] / D;     // 50000
    const int E = in_sizes[1] / 2;     // 640000
    const int NT = 1000;               // distinct t values

    size_t off = 0;
    auto carve = [&](size_t nbytes) -> void* {
        void* p = (void*)((char*)d_ws + off);
        off += (nbytes + 255) & ~(size_t)255;
        return p;
    };
    int*   flag   = (int*)carve(256);
    int*   deg    = (int*)carve((size_t)N * 4);
    int*   cursor = (int*)carve((size_t)N * 4);
    int*   rowptr = (int*)carve((size_t)(N + 1) * 4);
    float* dinv   = (float*)carve((size_t)N * 4);
    int*   csr    = (int*)carve((size_t)E * 4);
    float* WT     = (float*)carve((size_t)3 * 16384 * 4);
    float* table  = (float*)carve((size_t)NT * D * 4);
    float* xw     = (float*)carve((size_t)N * D * 4);
    float* acc    = (float*)carve((size_t)N * D * 4);
    (void)ws_size; (void)n_in; (void)out_size;

    const float* WT1  = WT;
    const float* WTt2 = WT + 16384;
    const float* WT2  = WT + 2 * 16384;

    hipMemsetAsync(deg, 0, (size_t)N * 4, stream);
    hipMemsetAsync(cursor, 0, (size_t)N * 4, stream);

    detect64_kernel<<<1, 256, 0, stream>>>(ep, flag, 2000);
    transpose3_kernel<<<192, 256, 0, stream>>>(W1, Wt2, W2, WT);
    count_deg_kernel<<<(E + 255) / 256, 256, 0, stream>>>(ep, flag, deg, E);
    scan_exclusive_kernel<<<1, 1024, 0, stream>>>(deg, rowptr, N);
    dinv_kernel<<<(N + 255) / 256, 256, 0, stream>>>(deg, dinv, N);
    fill_csr_kernel<<<(E + 255) / 256, 256, 0, stream>>>(ep, flag, rowptr, cursor, csr, E);

    // t_emb table: table[v] = gelu(v*Wt1+bt1) @ Wt2.T + bt2 + b1   (1000 rows)
    gemm128_v2<1><<<(NT + 127) / 128, 256, 0, stream>>>(
        nullptr, Wt1, bt1, WTt2, bt2, b1, nullptr, table, NT);
    // xw = dinv * (z @ W1.T)
    gemm128_v2<0><<<(N + 127) / 128, 256, 0, stream>>>(
        z, nullptr, nullptr, WT1, nullptr, nullptr, dinv, xw, N);
    // acc = elu( dinv*(sum of xw rows) + table[t] )     == elu(h1)
    gather_kernel<1><<<(N * 64 + 255) / 256, 256, 0, stream>>>(
        xw, dinv, rowptr, csr, table, t, nullptr, acc, N);
    // xw = dinv * (acc @ W2.T)
    gemm128_v2<0><<<(N + 127) / 128, 256, 0, stream>>>(
        acc, nullptr, nullptr, WT2, nullptr, nullptr, dinv, xw, N);
    // out = dinv*(sum of xw rows) + b2
    gather_kernel<0><<<(N * 64 + 255) / 256, 256, 0, stream>>>(
        xw, dinv, rowptr, csr, nullptr, nullptr, b2, out, N);
}

// Round 3
// 384.647 us; speedup vs baseline: 1.1803x; 1.1803x over previous
//
#include <hip/hip_runtime.h>
#include <hip/hip_bf16.h>
#include <math.h>

#define D 128

__device__ __forceinline__ float gelu_exact(float x) {
    return 0.5f * x * (1.0f + erff(x * 0.70710678118654752440f));
}
__device__ __forceinline__ float elu1(float x) {
    return x > 0.f ? x : expm1f(x);
}

// ---------------------------------------------------------------------------
// Detect whether edge_index buffer is int64 (high dwords all zero) or int32.
__global__ void detect64_kernel(const int* __restrict__ p, int* __restrict__ flag, int npairs) {
    __shared__ int any;
    if (threadIdx.x == 0) any = 0;
    __syncthreads();
    for (int i = threadIdx.x; i < npairs; i += blockDim.x) {
        if (p[2 * i + 1] != 0) any = 1;   // benign race
    }
    __syncthreads();
    if (threadIdx.x == 0) flag[0] = any ? 0 : 1;
}

// ---------------------------------------------------------------------------
__global__ void count_deg_kernel(const int* __restrict__ ep, const int* __restrict__ flag,
                                 int* __restrict__ deg, int E) {
    int e = blockIdx.x * blockDim.x + threadIdx.x;
    if (e >= E) return;
    int mode = flag[0];
    int c = mode ? ep[2 * (E + e)] : ep[E + e];
    atomicAdd(&deg[c], 1);
}

// ---------------------------------------------------------------------------
// Exclusive scan of deg[0..n) -> rowptr[0..n]. Single block, 1024 threads.
__global__ __launch_bounds__(1024) void scan_exclusive_kernel(const int* __restrict__ deg,
                                                              int* __restrict__ rowptr, int n) {
    __shared__ int wsum[16];
    __shared__ int carry_s;
    const int tid = threadIdx.x;
    const int lane = tid & 63;
    const int wv = tid >> 6;
    if (tid == 0) carry_s = 0;
    __syncthreads();
    for (int base = 0; base < n; base += 1024) {
        int idx = base + tid;
        int v = (idx < n) ? deg[idx] : 0;
        int s = v;
        #pragma unroll
        for (int off = 1; off < 64; off <<= 1) {
            int t = __shfl_up(s, off);
            if (lane >= off) s += t;
        }
        if (lane == 63) wsum[wv] = s;
        int c0 = carry_s;
        __syncthreads();
        if (wv == 0) {
            int ws = (lane < 16) ? wsum[lane] : 0;
            #pragma unroll
            for (int off = 1; off < 16; off <<= 1) {
                int t = __shfl_up(ws, off);
                if (lane >= off) ws += t;
            }
            if (lane < 16) wsum[lane] = ws;
        }
        __syncthreads();
        int woff = (wv == 0) ? 0 : wsum[wv - 1];
        if (idx < n) rowptr[idx] = c0 + woff + s - v;
        int total = wsum[15];
        __syncthreads();
        if (tid == 0) carry_s = c0 + total;
        __syncthreads();
    }
    if (threadIdx.x == 0) rowptr[n] = carry_s;
}

// ---------------------------------------------------------------------------
__global__ void dinv_kernel(const int* __restrict__ deg, float* __restrict__ dinv, int n) {
    int i = blockIdx.x * blockDim.x + threadIdx.x;
    if (i >= n) return;
    dinv[i] = 1.0f / sqrtf((float)(deg[i] + 1));   // +1 self loop
}

// ---------------------------------------------------------------------------
__global__ void fill_csr_kernel(const int* __restrict__ ep, const int* __restrict__ flag,
                                const int* __restrict__ rowptr, int* __restrict__ cursor,
                                int* __restrict__ csr, int E) {
    int e = blockIdx.x * blockDim.x + threadIdx.x;
    if (e >= E) return;
    int mode = flag[0];
    int r = mode ? ep[2 * e] : ep[e];
    int c = mode ? ep[2 * (E + e)] : ep[E + e];
    int pos = atomicAdd(&cursor[c], 1);
    csr[rowptr[c] + pos] = r;
}

// ---------------------------------------------------------------------------
// Transpose the three 128x128 weights into WT (k-major).
__global__ void transpose3_kernel(const float* __restrict__ W1, const float* __restrict__ Wt2,
                                  const float* __restrict__ W2, float* __restrict__ WT) {
    int idx = blockIdx.x * blockDim.x + threadIdx.x;   // 0 .. 3*16384
    int m = idx >> 14;
    int flat = idx & 16383;
    int j = flat >> 7, k = flat & 127;
    const float* src = (m == 0) ? W1 : ((m == 1) ? Wt2 : W2);
    WT[m * 16384 + k * 128 + j] = src[flat];
}

// ---------------------------------------------------------------------------
// G[v][k] = gelu(v * wt1[k] + bt1[k]) — one erff per thread, full parallelism.
__global__ void gelu_table_kernel(const float* __restrict__ wt1, const float* __restrict__ bt1,
                                  float* __restrict__ G, int nt) {
    int idx = blockIdx.x * blockDim.x + threadIdx.x;
    if (idx >= nt * D) return;
    int v = idx >> 7, k = idx & 127;
    G[idx] = gelu_exact(fmaf((float)v, wt1[k], bt1[k]));
}

// ---------------------------------------------------------------------------
// GEMM: out[r][j] = sum_k A[r][k] * WT[k][j]
//   128 rows/block, 256 threads (16x16), 8x8 micro-kernel.
//   Only W staged in LDS (66 KB -> 2 blocks/CU). A read direct from global:
//   16 lanes sharing an (r,k) fragment hit the SAME address -> HW broadcast.
// MODE 0: epilogue out = dinv[r] * acc
// MODE 2: epilogue out = acc + bias[j] + bias2[j]
template <int MODE>
__global__ __launch_bounds__(256) void gemm128_v2(
    const float* __restrict__ Ain,
    const float* __restrict__ WT,
    const float* __restrict__ bias, const float* __restrict__ bias2,
    const float* __restrict__ dinv,
    float* __restrict__ out, int n) {
    __shared__ float Wsh[128][132];
    const int tid = threadIdx.x;
    const int r0 = blockIdx.x * 128;

    // stage WT -> Wsh
    #pragma unroll
    for (int rep = 0; rep < 16; ++rep) {
        int flat = (rep * 256 + tid) * 4;
        int k = flat >> 7, j = flat & 127;
        *(float4*)&Wsh[k][j] = *(const float4*)(WT + flat);
    }
    __syncthreads();

    const int tx = tid & 15, ty = tid >> 4;
    const int rbase = r0 + ty * 8;

    float acc[8][8];
    #pragma unroll
    for (int i = 0; i < 8; ++i)
        #pragma unroll
        for (int j = 0; j < 8; ++j) acc[i][j] = 0.f;

    #pragma unroll 2
    for (int k0 = 0; k0 < 128; k0 += 4) {
        float4 a[8];
        #pragma unroll
        for (int i = 0; i < 8; ++i) {
            int rr = rbase + i;
            a[i] = (rr < n) ? *(const float4*)(Ain + (size_t)rr * D + k0)
                            : make_float4(0.f, 0.f, 0.f, 0.f);
        }
        float4 wv[4][2];
        #pragma unroll
        for (int kk = 0; kk < 4; ++kk) {
            wv[kk][0] = *(const float4*)&Wsh[k0 + kk][tx * 8];
            wv[kk][1] = *(const float4*)&Wsh[k0 + kk][tx * 8 + 4];
        }
        #pragma unroll
        for (int i = 0; i < 8; ++i) {
            float av[4] = {a[i].x, a[i].y, a[i].z, a[i].w};
            #pragma unroll
            for (int kk = 0; kk < 4; ++kk) {
                acc[i][0] = fmaf(av[kk], wv[kk][0].x, acc[i][0]);
                acc[i][1] = fmaf(av[kk], wv[kk][0].y, acc[i][1]);
                acc[i][2] = fmaf(av[kk], wv[kk][0].z, acc[i][2]);
                acc[i][3] = fmaf(av[kk], wv[kk][0].w, acc[i][3]);
                acc[i][4] = fmaf(av[kk], wv[kk][1].x, acc[i][4]);
                acc[i][5] = fmaf(av[kk], wv[kk][1].y, acc[i][5]);
                acc[i][6] = fmaf(av[kk], wv[kk][1].z, acc[i][6]);
                acc[i][7] = fmaf(av[kk], wv[kk][1].w, acc[i][7]);
            }
        }
    }

    float4 badd0 = make_float4(0.f, 0.f, 0.f, 0.f);
    float4 badd1 = make_float4(0.f, 0.f, 0.f, 0.f);
    if (MODE == 2) {
        float4 ba = *(const float4*)(bias + tx * 8);
        float4 bb = *(const float4*)(bias2 + tx * 8);
        badd0.x = ba.x + bb.x; badd0.y = ba.y + bb.y; badd0.z = ba.z + bb.z; badd0.w = ba.w + bb.w;
        ba = *(const float4*)(bias + tx * 8 + 4);
        bb = *(const float4*)(bias2 + tx * 8 + 4);
        badd1.x = ba.x + bb.x; badd1.y = ba.y + bb.y; badd1.z = ba.z + bb.z; badd1.w = ba.w + bb.w;
    }
    #pragma unroll
    for (int i = 0; i < 8; ++i) {
        int rr = rbase + i;
        if (rr < n) {
            float scale = (MODE == 0) ? dinv[rr] : 1.f;
            float4 o0, o1;
            o0.x = acc[i][0] * scale + badd0.x;
            o0.y = acc[i][1] * scale + badd0.y;
            o0.z = acc[i][2] * scale + badd0.z;
            o0.w = acc[i][3] * scale + badd0.w;
            o1.x = acc[i][4] * scale + badd1.x;
            o1.y = acc[i][5] * scale + badd1.y;
            o1.z = acc[i][6] * scale + badd1.z;
            o1.w = acc[i][7] * scale + badd1.w;
            *(float4*)(out + (size_t)rr * D + tx * 8) = o0;
            *(float4*)(out + (size_t)rr * D + tx * 8 + 4) = o1;
        }
    }
}

// ---------------------------------------------------------------------------
// Gather-aggregation over pre-scaled rows xw' (already multiplied by dinv[src]).
//   sum = xw'[i] + sum_{r in in(i)} xw'[r];  val = dinv[i]*sum
// EPI 0: dst[i] = val + bias              (final output + b2)
// EPI 1: dst[i] = elu(val + table[t[i]])  (h1 path, elu pre-applied for GEMM2)
template <int EPI>
__global__ __launch_bounds__(256) void gather_kernel(
    const float* __restrict__ xw, const float* __restrict__ dinv,
    const int* __restrict__ rowptr, const int* __restrict__ csr,
    const float* __restrict__ table, const int* __restrict__ tvec,
    const float* __restrict__ bias,
    float* __restrict__ dst, int n) {
    int wid = (blockIdx.x * 256 + threadIdx.x) >> 6;
    if (wid >= n) return;
    int lane = threadIdx.x & 63;
    const size_t lo = (size_t)lane * 2;

    // independent epilogue operands issued early
    float di = dinv[wid];
    float2 ep;
    if (EPI == 0) {
        ep = *(const float2*)(bias + lo);
    } else {
        int tv = tvec[wid];
        ep = *(const float2*)(table + (size_t)tv * D + lo);
    }

    float2 s = *(const float2*)(xw + (size_t)wid * D + lo);
    float sx = s.x, sy = s.y;
    int e = rowptr[wid], e1 = rowptr[wid + 1];
    for (; e + 4 <= e1; e += 4) {
        int r0 = csr[e], r1 = csr[e + 1], r2 = csr[e + 2], r3 = csr[e + 3];
        float2 u0 = *(const float2*)(xw + (size_t)r0 * D + lo);
        float2 u1 = *(const float2*)(xw + (size_t)r1 * D + lo);
        float2 u2 = *(const float2*)(xw + (size_t)r2 * D + lo);
        float2 u3 = *(const float2*)(xw + (size_t)r3 * D + lo);
        sx += (u0.x + u1.x) + (u2.x + u3.x);
        sy += (u0.y + u1.y) + (u2.y + u3.y);
    }
    if (e + 2 <= e1) {
        int r0 = csr[e], r1 = csr[e + 1];
        float2 u0 = *(const float2*)(xw + (size_t)r0 * D + lo);
        float2 u1 = *(const float2*)(xw + (size_t)r1 * D + lo);
        sx += u0.x + u1.x;
        sy += u0.y + u1.y;
        e += 2;
    }
    if (e < e1) {
        int r0 = csr[e];
        float2 u0 = *(const float2*)(xw + (size_t)r0 * D + lo);
        sx += u0.x;
        sy += u0.y;
    }

    float2 o;
    if (EPI == 0) {
        o.x = di * sx + ep.x;
        o.y = di * sy + ep.y;
    } else {
        o.x = elu1(di * sx + ep.x);
        o.y = elu1(di * sy + ep.y);
    }
    *(float2*)(dst + (size_t)wid * D + lo) = o;
}

// ---------------------------------------------------------------------------
extern "C" void kernel_launch(void* const* d_in, const int* in_sizes, int n_in,
                              void* d_out, int out_size, void* d_ws, size_t ws_size,
                              hipStream_t stream) {
    const float* z   = (const float*)d_in[0];
    const int*   ep  = (const int*)d_in[1];
    const int*   t   = (const int*)d_in[2];
    const float* Wt1 = (const float*)d_in[3];
    const float* bt1 = (const float*)d_in[4];
    const float* Wt2 = (const float*)d_in[5];
    const float* bt2 = (const float*)d_in[6];
    const float* W1  = (const float*)d_in[7];
    const float* b1  = (const float*)d_in[8];
    const float* W2  = (const float*)d_in[9];
    const float* b2  = (const float*)d_in[10];
    float* out = (float*)d_out;

    const int N = in_sizes[0] / D;     // 50000
    const int E = in_sizes[1] / 2;     // 640000
    const int NT = 1000;               // distinct t values

    size_t off = 0;
    auto carve = [&](size_t nbytes) -> void* {
        void* p = (void*)((char*)d_ws + off);
        off += (nbytes + 255) & ~(size_t)255;
        return p;
    };
    int*   flag   = (int*)carve(256);
    int*   deg    = (int*)carve((size_t)N * 4);
    int*   cursor = (int*)carve((size_t)N * 4);
    int*   rowptr = (int*)carve((size_t)(N + 1) * 4);
    float* dinv   = (float*)carve((size_t)N * 4);
    int*   csr    = (int*)carve((size_t)E * 4);
    float* WT     = (float*)carve((size_t)3 * 16384 * 4);
    float* G      = (float*)carve((size_t)NT * D * 4);
    float* table  = (float*)carve((size_t)NT * D * 4);
    float* xw     = (float*)carve((size_t)N * D * 4);
    float* acc    = (float*)carve((size_t)N * D * 4);
    (void)ws_size; (void)n_in; (void)out_size;

    const float* WT1  = WT;
    const float* WTt2 = WT + 16384;
    const float* WT2  = WT + 2 * 16384;

    hipMemsetAsync(deg, 0, (size_t)N * 4, stream);
    hipMemsetAsync(cursor, 0, (size_t)N * 4, stream);

    detect64_kernel<<<1, 256, 0, stream>>>(ep, flag, 2000);
    transpose3_kernel<<<192, 256, 0, stream>>>(W1, Wt2, W2, WT);
    gelu_table_kernel<<<(NT * D + 255) / 256, 256, 0, stream>>>(Wt1, bt1, G, NT);
    count_deg_kernel<<<(E + 255) / 256, 256, 0, stream>>>(ep, flag, deg, E);
    scan_exclusive_kernel<<<1, 1024, 0, stream>>>(deg, rowptr, N);
    dinv_kernel<<<(N + 255) / 256, 256, 0, stream>>>(deg, dinv, N);
    fill_csr_kernel<<<(E + 255) / 256, 256, 0, stream>>>(ep, flag, rowptr, cursor, csr, E);

    // t_emb table: table = G @ Wt2.T + bt2 + b1   (1000 rows)
    gemm128_v2<2><<<(NT + 127) / 128, 256, 0, stream>>>(
        G, WTt2, bt2, b1, nullptr, table, NT);
    // xw = dinv * (z @ W1.T)
    gemm128_v2<0><<<(N + 127) / 128, 256, 0, stream>>>(
        z, WT1, nullptr, nullptr, dinv, xw, N);
    // acc = elu( dinv*(sum of xw rows) + table[t] )     == elu(h1)
    gather_kernel<1><<<(N * 64 + 255) / 256, 256, 0, stream>>>(
        xw, dinv, rowptr, csr, table, t, nullptr, acc, N);
    // xw = dinv * (acc @ W2.T)
    gemm128_v2<0><<<(N + 127) / 128, 256, 0, stream>>>(
        acc, WT2, nullptr, nullptr, dinv, xw, N);
    // out = dinv*(sum of xw rows) + b2
    gather_kernel<0><<<(N * 64 + 255) / 256, 256, 0, stream>>>(
        xw, dinv, rowptr, csr, nullptr, nullptr, b2, out, N);
}

// Round 4
// 361.033 us; speedup vs baseline: 1.2575x; 1.0654x over previous
//
#include <hip/hip_runtime.h>
#include <hip/hip_bf16.h>
#include <math.h>

#define D 128

__device__ __forceinline__ float gelu_exact(float x) {
    return 0.5f * x * (1.0f + erff(x * 0.70710678118654752440f));
}
__device__ __forceinline__ float elu1(float x) {
    return x > 0.f ? x : expm1f(x);
}

// ---------------------------------------------------------------------------
// Detect whether edge_index buffer is int64 (high dwords all zero) or int32.
__global__ void detect64_kernel(const int* __restrict__ p, int* __restrict__ flag, int npairs) {
    __shared__ int any;
    if (threadIdx.x == 0) any = 0;
    __syncthreads();
    for (int i = threadIdx.x; i < npairs; i += blockDim.x) {
        if (p[2 * i + 1] != 0) any = 1;   // benign race
    }
    __syncthreads();
    if (threadIdx.x == 0) flag[0] = any ? 0 : 1;
}

// ---------------------------------------------------------------------------
__global__ void count_deg_kernel(const int* __restrict__ ep, const int* __restrict__ flag,
                                 int* __restrict__ deg, int E) {
    int e = blockIdx.x * blockDim.x + threadIdx.x;
    if (e >= E) return;
    int mode = flag[0];
    int c = mode ? ep[2 * (E + e)] : ep[E + e];
    atomicAdd(&deg[c], 1);
}

// ---------------------------------------------------------------------------
// Exclusive scan of deg[0..n) -> rowptr[0..n]. Single block, 1024 threads.
__global__ __launch_bounds__(1024) void scan_exclusive_kernel(const int* __restrict__ deg,
                                                              int* __restrict__ rowptr, int n) {
    __shared__ int wsum[16];
    __shared__ int carry_s;
    const int tid = threadIdx.x;
    const int lane = tid & 63;
    const int wv = tid >> 6;
    if (tid == 0) carry_s = 0;
    __syncthreads();
    for (int base = 0; base < n; base += 1024) {
        int idx = base + tid;
        int v = (idx < n) ? deg[idx] : 0;
        int s = v;
        #pragma unroll
        for (int off = 1; off < 64; off <<= 1) {
            int t = __shfl_up(s, off);
            if (lane >= off) s += t;
        }
        if (lane == 63) wsum[wv] = s;
        int c0 = carry_s;
        __syncthreads();
        if (wv == 0) {
            int ws = (lane < 16) ? wsum[lane] : 0;
            #pragma unroll
            for (int off = 1; off < 16; off <<= 1) {
                int t = __shfl_up(ws, off);
                if (lane >= off) ws += t;
            }
            if (lane < 16) wsum[lane] = ws;
        }
        __syncthreads();
        int woff = (wv == 0) ? 0 : wsum[wv - 1];
        if (idx < n) rowptr[idx] = c0 + woff + s - v;
        int total = wsum[15];
        __syncthreads();
        if (tid == 0) carry_s = c0 + total;
        __syncthreads();
    }
    if (threadIdx.x == 0) rowptr[n] = carry_s;
}

// ---------------------------------------------------------------------------
__global__ void dinv_kernel(const int* __restrict__ deg, float* __restrict__ dinv, int n) {
    int i = blockIdx.x * blockDim.x + threadIdx.x;
    if (i >= n) return;
    dinv[i] = 1.0f / sqrtf((float)(deg[i] + 1));   // +1 self loop
}

// ---------------------------------------------------------------------------
__global__ void fill_csr_kernel(const int* __restrict__ ep, const int* __restrict__ flag,
                                const int* __restrict__ rowptr, int* __restrict__ cursor,
                                int* __restrict__ csr, int E) {
    int e = blockIdx.x * blockDim.x + threadIdx.x;
    if (e >= E) return;
    int mode = flag[0];
    int r = mode ? ep[2 * e] : ep[e];
    int c = mode ? ep[2 * (E + e)] : ep[E + e];
    int pos = atomicAdd(&cursor[c], 1);
    csr[rowptr[c] + pos] = r;
}

// ---------------------------------------------------------------------------
// Transpose the three 128x128 weights into WT (k-major).
__global__ void transpose3_kernel(const float* __restrict__ W1, const float* __restrict__ Wt2,
                                  const float* __restrict__ W2, float* __restrict__ WT) {
    int idx = blockIdx.x * blockDim.x + threadIdx.x;   // 0 .. 3*16384
    int m = idx >> 14;
    int flat = idx & 16383;
    int j = flat >> 7, k = flat & 127;
    const float* src = (m == 0) ? W1 : ((m == 1) ? Wt2 : W2);
    WT[m * 16384 + k * 128 + j] = src[flat];
}

// ---------------------------------------------------------------------------
// G[v][k] = gelu(v * wt1[k] + bt1[k]) — one erff per thread, full parallelism.
__global__ void gelu_table_kernel(const float* __restrict__ wt1, const float* __restrict__ bt1,
                                  float* __restrict__ G, int nt) {
    int idx = blockIdx.x * blockDim.x + threadIdx.x;
    if (idx >= nt * D) return;
    int v = idx >> 7, k = idx & 127;
    G[idx] = gelu_exact(fmaf((float)v, wt1[k], bt1[k]));
}

// ---------------------------------------------------------------------------
// GEMM v3: out[r][j] = sum_k A[r][k] * WT[k][j]
//   Block = 128 rows x 64 cols (blockIdx.y = col half). 256 threads:
//   tx = tid&7 -> 8 cols each; ty = tid>>3 -> 4 rows each. 4x8 micro-tile.
//   W tile 128x64 fp32 in LDS (stride 68 -> 2-way bank alias = free).
//   34.8 KB LDS -> 4 blocks/CU. A read direct from global (8-lane broadcast).
// MODE 0: epilogue out = dinv[r] * acc
// MODE 2: epilogue out = acc + bias[j] + bias2[j]
template <int MODE>
__global__ __launch_bounds__(256) void gemm128_v3(
    const float* __restrict__ Ain,
    const float* __restrict__ WT,
    const float* __restrict__ bias, const float* __restrict__ bias2,
    const float* __restrict__ dinv,
    float* __restrict__ out, int n) {
    __shared__ float Wsh[128][68];
    const int tid = threadIdx.x;
    const int r0 = blockIdx.x * 128;
    const int jb = blockIdx.y * 64;

    // stage WT[k][jb..jb+64) -> Wsh  (2048 float4 / 256 threads = 8 reps)
    #pragma unroll
    for (int rep = 0; rep < 8; ++rep) {
        int flat = rep * 256 + tid;
        int k = flat >> 4;
        int jj = (flat & 15) * 4;
        *(float4*)&Wsh[k][jj] = *(const float4*)(WT + k * D + jb + jj);
    }
    __syncthreads();

    const int tx = tid & 7, ty = tid >> 3;
    const int rbase = r0 + ty * 4;
    const int jcol = tx * 8;

    float acc[4][8];
    #pragma unroll
    for (int i = 0; i < 4; ++i)
        #pragma unroll
        for (int j = 0; j < 8; ++j) acc[i][j] = 0.f;

    #pragma unroll 2
    for (int k0 = 0; k0 < 128; k0 += 4) {
        float4 a[4];
        #pragma unroll
        for (int i = 0; i < 4; ++i) {
            int rr = rbase + i;
            a[i] = (rr < n) ? *(const float4*)(Ain + (size_t)rr * D + k0)
                            : make_float4(0.f, 0.f, 0.f, 0.f);
        }
        float4 wv[4][2];
        #pragma unroll
        for (int kk = 0; kk < 4; ++kk) {
            wv[kk][0] = *(const float4*)&Wsh[k0 + kk][jcol];
            wv[kk][1] = *(const float4*)&Wsh[k0 + kk][jcol + 4];
        }
        #pragma unroll
        for (int i = 0; i < 4; ++i) {
            float av[4] = {a[i].x, a[i].y, a[i].z, a[i].w};
            #pragma unroll
            for (int kk = 0; kk < 4; ++kk) {
                acc[i][0] = fmaf(av[kk], wv[kk][0].x, acc[i][0]);
                acc[i][1] = fmaf(av[kk], wv[kk][0].y, acc[i][1]);
                acc[i][2] = fmaf(av[kk], wv[kk][0].z, acc[i][2]);
                acc[i][3] = fmaf(av[kk], wv[kk][0].w, acc[i][3]);
                acc[i][4] = fmaf(av[kk], wv[kk][1].x, acc[i][4]);
                acc[i][5] = fmaf(av[kk], wv[kk][1].y, acc[i][5]);
                acc[i][6] = fmaf(av[kk], wv[kk][1].z, acc[i][6]);
                acc[i][7] = fmaf(av[kk], wv[kk][1].w, acc[i][7]);
            }
        }
    }

    float4 badd0 = make_float4(0.f, 0.f, 0.f, 0.f);
    float4 badd1 = make_float4(0.f, 0.f, 0.f, 0.f);
    if (MODE == 2) {
        float4 ba = *(const float4*)(bias + jb + jcol);
        float4 bb = *(const float4*)(bias2 + jb + jcol);
        badd0.x = ba.x + bb.x; badd0.y = ba.y + bb.y; badd0.z = ba.z + bb.z; badd0.w = ba.w + bb.w;
        ba = *(const float4*)(bias + jb + jcol + 4);
        bb = *(const float4*)(bias2 + jb + jcol + 4);
        badd1.x = ba.x + bb.x; badd1.y = ba.y + bb.y; badd1.z = ba.z + bb.z; badd1.w = ba.w + bb.w;
    }
    #pragma unroll
    for (int i = 0; i < 4; ++i) {
        int rr = rbase + i;
        if (rr < n) {
            float scale = (MODE == 0) ? dinv[rr] : 1.f;
            float4 o0, o1;
            o0.x = acc[i][0] * scale + badd0.x;
            o0.y = acc[i][1] * scale + badd0.y;
            o0.z = acc[i][2] * scale + badd0.z;
            o0.w = acc[i][3] * scale + badd0.w;
            o1.x = acc[i][4] * scale + badd1.x;
            o1.y = acc[i][5] * scale + badd1.y;
            o1.z = acc[i][6] * scale + badd1.z;
            o1.w = acc[i][7] * scale + badd1.w;
            *(float4*)(out + (size_t)rr * D + jb + jcol) = o0;
            *(float4*)(out + (size_t)rr * D + jb + jcol + 4) = o1;
        }
    }
}

// ---------------------------------------------------------------------------
// Gather-aggregation over pre-scaled rows xw' (already multiplied by dinv[src]).
//   sum = xw'[i] + sum_{r in in(i)} xw'[r];  val = dinv[i]*sum
// EPI 0: dst[i] = val + bias              (final output + b2)
// EPI 1: dst[i] = elu(val + table[t[i]])  (h1 path, elu pre-applied for GEMM2)
template <int EPI>
__global__ __launch_bounds__(256) void gather_kernel(
    const float* __restrict__ xw, const float* __restrict__ dinv,
    const int* __restrict__ rowptr, const int* __restrict__ csr,
    const float* __restrict__ table, const int* __restrict__ tvec,
    const float* __restrict__ bias,
    float* __restrict__ dst, int n) {
    int wid = (blockIdx.x * 256 + threadIdx.x) >> 6;
    if (wid >= n) return;
    int lane = threadIdx.x & 63;
    const size_t lo = (size_t)lane * 2;

    // independent epilogue operands issued early
    float di = dinv[wid];
    float2 ep;
    if (EPI == 0) {
        ep = *(const float2*)(bias + lo);
    } else {
        int tv = tvec[wid];
        ep = *(const float2*)(table + (size_t)tv * D + lo);
    }

    float2 s = *(const float2*)(xw + (size_t)wid * D + lo);
    float sx = s.x, sy = s.y;
    int e = rowptr[wid], e1 = rowptr[wid + 1];
    for (; e + 8 <= e1; e += 8) {
        int r0 = csr[e],     r1 = csr[e + 1], r2 = csr[e + 2], r3 = csr[e + 3];
        int r4 = csr[e + 4], r5 = csr[e + 5], r6 = csr[e + 6], r7 = csr[e + 7];
        float2 u0 = *(const float2*)(xw + (size_t)r0 * D + lo);
        float2 u1 = *(const float2*)(xw + (size_t)r1 * D + lo);
        float2 u2 = *(const float2*)(xw + (size_t)r2 * D + lo);
        float2 u3 = *(const float2*)(xw + (size_t)r3 * D + lo);
        float2 u4 = *(const float2*)(xw + (size_t)r4 * D + lo);
        float2 u5 = *(const float2*)(xw + (size_t)r5 * D + lo);
        float2 u6 = *(const float2*)(xw + (size_t)r6 * D + lo);
        float2 u7 = *(const float2*)(xw + (size_t)r7 * D + lo);
        sx += ((u0.x + u1.x) + (u2.x + u3.x)) + ((u4.x + u5.x) + (u6.x + u7.x));
        sy += ((u0.y + u1.y) + (u2.y + u3.y)) + ((u4.y + u5.y) + (u6.y + u7.y));
    }
    if (e + 4 <= e1) {
        int r0 = csr[e], r1 = csr[e + 1], r2 = csr[e + 2], r3 = csr[e + 3];
        float2 u0 = *(const float2*)(xw + (size_t)r0 * D + lo);
        float2 u1 = *(const float2*)(xw + (size_t)r1 * D + lo);
        float2 u2 = *(const float2*)(xw + (size_t)r2 * D + lo);
        float2 u3 = *(const float2*)(xw + (size_t)r3 * D + lo);
        sx += (u0.x + u1.x) + (u2.x + u3.x);
        sy += (u0.y + u1.y) + (u2.y + u3.y);
        e += 4;
    }
    if (e + 2 <= e1) {
        int r0 = csr[e], r1 = csr[e + 1];
        float2 u0 = *(const float2*)(xw + (size_t)r0 * D + lo);
        float2 u1 = *(const float2*)(xw + (size_t)r1 * D + lo);
        sx += u0.x + u1.x;
        sy += u0.y + u1.y;
        e += 2;
    }
    if (e < e1) {
        int r0 = csr[e];
        float2 u0 = *(const float2*)(xw + (size_t)r0 * D + lo);
        sx += u0.x;
        sy += u0.y;
    }

    float2 o;
    if (EPI == 0) {
        o.x = di * sx + ep.x;
        o.y = di * sy + ep.y;
    } else {
        o.x = elu1(di * sx + ep.x);
        o.y = elu1(di * sy + ep.y);
    }
    *(float2*)(dst + (size_t)wid * D + lo) = o;
}

// ---------------------------------------------------------------------------
extern "C" void kernel_launch(void* const* d_in, const int* in_sizes, int n_in,
                              void* d_out, int out_size, void* d_ws, size_t ws_size,
                              hipStream_t stream) {
    const float* z   = (const float*)d_in[0];
    const int*   ep  = (const int*)d_in[1];
    const int*   t   = (const int*)d_in[2];
    const float* Wt1 = (const float*)d_in[3];
    const float* bt1 = (const float*)d_in[4];
    const float* Wt2 = (const float*)d_in[5];
    const float* bt2 = (const float*)d_in[6];
    const float* W1  = (const float*)d_in[7];
    const float* b1  = (const float*)d_in[8];
    const float* W2  = (const float*)d_in[9];
    const float* b2  = (const float*)d_in[10];
    float* out = (float*)d_out;

    const int N = in_sizes[0] / D;     // 50000
    const int E = in_sizes[1] / 2;     // 640000
    const int NT = 1000;               // distinct t values

    size_t off = 0;
    auto carve = [&](size_t nbytes) -> void* {
        void* p = (void*)((char*)d_ws + off);
        off += (nbytes + 255) & ~(size_t)255;
        return p;
    };
    int*   flag   = (int*)carve(256);
    int*   deg    = (int*)carve((size_t)N * 4);
    int*   cursor = (int*)carve((size_t)N * 4);
    int*   rowptr = (int*)carve((size_t)(N + 1) * 4);
    float* dinv   = (float*)carve((size_t)N * 4);
    int*   csr    = (int*)carve((size_t)E * 4);
    float* WT     = (float*)carve((size_t)3 * 16384 * 4);
    float* G      = (float*)carve((size_t)NT * D * 4);
    float* table  = (float*)carve((size_t)NT * D * 4);
    float* xw     = (float*)carve((size_t)N * D * 4);
    float* acc    = (float*)carve((size_t)N * D * 4);
    (void)ws_size; (void)n_in; (void)out_size;

    const float* WT1  = WT;
    const float* WTt2 = WT + 16384;
    const float* WT2  = WT + 2 * 16384;

    hipMemsetAsync(deg, 0, (size_t)N * 4, stream);
    hipMemsetAsync(cursor, 0, (size_t)N * 4, stream);

    detect64_kernel<<<1, 256, 0, stream>>>(ep, flag, 2000);
    transpose3_kernel<<<192, 256, 0, stream>>>(W1, Wt2, W2, WT);
    gelu_table_kernel<<<(NT * D + 255) / 256, 256, 0, stream>>>(Wt1, bt1, G, NT);
    count_deg_kernel<<<(E + 255) / 256, 256, 0, stream>>>(ep, flag, deg, E);
    scan_exclusive_kernel<<<1, 1024, 0, stream>>>(deg, rowptr, N);
    dinv_kernel<<<(N + 255) / 256, 256, 0, stream>>>(deg, dinv, N);
    fill_csr_kernel<<<(E + 255) / 256, 256, 0, stream>>>(ep, flag, rowptr, cursor, csr, E);

    dim3 gemm_grid_n((N + 127) / 128, 2);
    dim3 gemm_grid_t((NT + 127) / 128, 2);
    // t_emb table: table = G @ Wt2.T + bt2 + b1   (1000 rows)
    gemm128_v3<2><<<gemm_grid_t, 256, 0, stream>>>(
        G, WTt2, bt2, b1, nullptr, table, NT);
    // xw = dinv * (z @ W1.T)
    gemm128_v3<0><<<gemm_grid_n, 256, 0, stream>>>(
        z, WT1, nullptr, nullptr, dinv, xw, N);
    // acc = elu( dinv*(sum of xw rows) + table[t] )     == elu(h1)
    gather_kernel<1><<<(N * 64 + 255) / 256, 256, 0, stream>>>(
        xw, dinv, rowptr, csr, table, t, nullptr, acc, N);
    // xw = dinv * (acc @ W2.T)
    gemm128_v3<0><<<gemm_grid_n, 256, 0, stream>>>(
        acc, WT2, nullptr, nullptr, dinv, xw, N);
    // out = dinv*(sum of xw rows) + b2
    gather_kernel<0><<<(N * 64 + 255) / 256, 256, 0, stream>>>(
        xw, dinv, rowptr, csr, nullptr, nullptr, b2, out, N);
}

// Round 5
// 249.760 us; speedup vs baseline: 1.8178x; 1.4455x over previous
//
#include <hip/hip_runtime.h>
#include <hip/hip_bf16.h>
#include <math.h>

#define D 128

typedef __attribute__((ext_vector_type(8))) short short8v;
typedef __attribute__((ext_vector_type(4))) float f32x4;

__device__ __forceinline__ float gelu_exact(float x) {
    return 0.5f * x * (1.0f + erff(x * 0.70710678118654752440f));
}
__device__ __forceinline__ float elu1(float x) {
    return x > 0.f ? x : expm1f(x);
}
__device__ __forceinline__ unsigned short f2bf(float f) {   // RNE fp32->bf16 bits
    unsigned int u = __float_as_uint(f);
    u += 0x7fffu + ((u >> 16) & 1u);
    return (unsigned short)(u >> 16);
}
__device__ __forceinline__ float bflo(unsigned int u) {     // low bf16 of packed pair
    return __uint_as_float(u << 16);
}
__device__ __forceinline__ float bfhi(unsigned int u) {     // high bf16 of packed pair
    return __uint_as_float(u & 0xffff0000u);
}

// ---------------------------------------------------------------------------
__global__ void detect64_kernel(const int* __restrict__ p, int* __restrict__ flag, int npairs) {
    __shared__ int any;
    if (threadIdx.x == 0) any = 0;
    __syncthreads();
    for (int i = threadIdx.x; i < npairs; i += blockDim.x) {
        if (p[2 * i + 1] != 0) any = 1;   // benign race
    }
    __syncthreads();
    if (threadIdx.x == 0) flag[0] = any ? 0 : 1;
}

// ---------------------------------------------------------------------------
__global__ void count_deg_kernel(const int* __restrict__ ep, const int* __restrict__ flag,
                                 int* __restrict__ deg, int E) {
    int e = blockIdx.x * blockDim.x + threadIdx.x;
    if (e >= E) return;
    int mode = flag[0];
    int c = mode ? ep[2 * (E + e)] : ep[E + e];
    atomicAdd(&deg[c], 1);
}

// ---------------------------------------------------------------------------
__global__ __launch_bounds__(1024) void scan_exclusive_kernel(const int* __restrict__ deg,
                                                              int* __restrict__ rowptr, int n) {
    __shared__ int wsum[16];
    __shared__ int carry_s;
    const int tid = threadIdx.x;
    const int lane = tid & 63;
    const int wv = tid >> 6;
    if (tid == 0) carry_s = 0;
    __syncthreads();
    for (int base = 0; base < n; base += 1024) {
        int idx = base + tid;
        int v = (idx < n) ? deg[idx] : 0;
        int s = v;
        #pragma unroll
        for (int off = 1; off < 64; off <<= 1) {
            int t = __shfl_up(s, off);
            if (lane >= off) s += t;
        }
        if (lane == 63) wsum[wv] = s;
        int c0 = carry_s;
        __syncthreads();
        if (wv == 0) {
            int ws = (lane < 16) ? wsum[lane] : 0;
            #pragma unroll
            for (int off = 1; off < 16; off <<= 1) {
                int t = __shfl_up(ws, off);
                if (lane >= off) ws += t;
            }
            if (lane < 16) wsum[lane] = ws;
        }
        __syncthreads();
        int woff = (wv == 0) ? 0 : wsum[wv - 1];
        if (idx < n) rowptr[idx] = c0 + woff + s - v;
        int total = wsum[15];
        __syncthreads();
        if (tid == 0) carry_s = c0 + total;
        __syncthreads();
    }
    if (threadIdx.x == 0) rowptr[n] = carry_s;
}

// ---------------------------------------------------------------------------
__global__ void dinv_kernel(const int* __restrict__ deg, float* __restrict__ dinv, int n) {
    int i = blockIdx.x * blockDim.x + threadIdx.x;
    if (i >= n) return;
    dinv[i] = 1.0f / sqrtf((float)(deg[i] + 1));   // +1 self loop
}

// ---------------------------------------------------------------------------
__global__ void fill_csr_kernel(const int* __restrict__ ep, const int* __restrict__ flag,
                                const int* __restrict__ rowptr, int* __restrict__ cursor,
                                int* __restrict__ csr, int E) {
    int e = blockIdx.x * blockDim.x + threadIdx.x;
    if (e >= E) return;
    int mode = flag[0];
    int r = mode ? ep[2 * e] : ep[e];
    int c = mode ? ep[2 * (E + e)] : ep[E + e];
    int pos = atomicAdd(&cursor[c], 1);
    csr[rowptr[c] + pos] = r;
}

// ---------------------------------------------------------------------------
// Transpose Wt2 (k-major) for the fp32 table GEMM.
__global__ void transpose_wt2_kernel(const float* __restrict__ Wt2, float* __restrict__ WT) {
    int idx = blockIdx.x * blockDim.x + threadIdx.x;   // 0..16384
    if (idx >= 16384) return;
    int j = idx >> 7, k = idx & 127;
    WT[k * 128 + j] = Wt2[idx];
}

// ---------------------------------------------------------------------------
// G[v][k] = gelu(v * wt1[k] + bt1[k])
__global__ void gelu_table_kernel(const float* __restrict__ wt1, const float* __restrict__ bt1,
                                  float* __restrict__ G, int nt) {
    int idx = blockIdx.x * blockDim.x + threadIdx.x;
    if (idx >= nt * D) return;
    int v = idx >> 7, k = idx & 127;
    G[idx] = gelu_exact(fmaf((float)v, wt1[k], bt1[k]));
}

// ---------------------------------------------------------------------------
// fp32 GEMM (table path only, 1000 rows): out = A @ WT + bias + bias2
__global__ __launch_bounds__(256) void gemm128_v3(
    const float* __restrict__ Ain,
    const float* __restrict__ WT,
    const float* __restrict__ bias, const float* __restrict__ bias2,
    float* __restrict__ out, int n) {
    __shared__ float Wsh[128][68];
    const int tid = threadIdx.x;
    const int r0 = blockIdx.x * 128;
    const int jb = blockIdx.y * 64;

    #pragma unroll
    for (int rep = 0; rep < 8; ++rep) {
        int flat = rep * 256 + tid;
        int k = flat >> 4;
        int jj = (flat & 15) * 4;
        *(float4*)&Wsh[k][jj] = *(const float4*)(WT + k * D + jb + jj);
    }
    __syncthreads();

    const int tx = tid & 7, ty = tid >> 3;
    const int rbase = r0 + ty * 4;
    const int jcol = tx * 8;

    float acc[4][8];
    #pragma unroll
    for (int i = 0; i < 4; ++i)
        #pragma unroll
        for (int j = 0; j < 8; ++j) acc[i][j] = 0.f;

    #pragma unroll 2
    for (int k0 = 0; k0 < 128; k0 += 4) {
        float4 a[4];
        #pragma unroll
        for (int i = 0; i < 4; ++i) {
            int rr = rbase + i;
            a[i] = (rr < n) ? *(const float4*)(Ain + (size_t)rr * D + k0)
                            : make_float4(0.f, 0.f, 0.f, 0.f);
        }
        float4 wv[4][2];
        #pragma unroll
        for (int kk = 0; kk < 4; ++kk) {
            wv[kk][0] = *(const float4*)&Wsh[k0 + kk][jcol];
            wv[kk][1] = *(const float4*)&Wsh[k0 + kk][jcol + 4];
        }
        #pragma unroll
        for (int i = 0; i < 4; ++i) {
            float av[4] = {a[i].x, a[i].y, a[i].z, a[i].w};
            #pragma unroll
            for (int kk = 0; kk < 4; ++kk) {
                acc[i][0] = fmaf(av[kk], wv[kk][0].x, acc[i][0]);
                acc[i][1] = fmaf(av[kk], wv[kk][0].y, acc[i][1]);
                acc[i][2] = fmaf(av[kk], wv[kk][0].z, acc[i][2]);
                acc[i][3] = fmaf(av[kk], wv[kk][0].w, acc[i][3]);
                acc[i][4] = fmaf(av[kk], wv[kk][1].x, acc[i][4]);
                acc[i][5] = fmaf(av[kk], wv[kk][1].y, acc[i][5]);
                acc[i][6] = fmaf(av[kk], wv[kk][1].z, acc[i][6]);
                acc[i][7] = fmaf(av[kk], wv[kk][1].w, acc[i][7]);
            }
        }
    }

    float4 ba = *(const float4*)(bias + jb + jcol);
    float4 bb = *(const float4*)(bias2 + jb + jcol);
    float4 badd0 = make_float4(ba.x + bb.x, ba.y + bb.y, ba.z + bb.z, ba.w + bb.w);
    ba = *(const float4*)(bias + jb + jcol + 4);
    bb = *(const float4*)(bias2 + jb + jcol + 4);
    float4 badd1 = make_float4(ba.x + bb.x, ba.y + bb.y, ba.z + bb.z, ba.w + bb.w);
    #pragma unroll
    for (int i = 0; i < 4; ++i) {
        int rr = rbase + i;
        if (rr < n) {
            float4 o0, o1;
            o0.x = acc[i][0] + badd0.x; o0.y = acc[i][1] + badd0.y;
            o0.z = acc[i][2] + badd0.z; o0.w = acc[i][3] + badd0.w;
            o1.x = acc[i][4] + badd1.x; o1.y = acc[i][5] + badd1.y;
            o1.z = acc[i][6] + badd1.z; o1.w = acc[i][7] + badd1.w;
            *(float4*)(out + (size_t)rr * D + jb + jcol) = o0;
            *(float4*)(out + (size_t)rr * D + jb + jcol + 4) = o1;
        }
    }
}

// ---------------------------------------------------------------------------
// bf16 MFMA GEMM: outh[r][j] = bf16( dinv[r] * sum_k A[r][k] * W[j][k] )
// Swapped operands: D^T = W · A^T  (mfma 16x16x32 bf16).
//   A-operand = W (row-major [j][k], bf16-converted into LDS, rows padded to 136)
//   B-operand lane l: A[rb + rt*16 + (l&15)][K0 + (l>>4)*8 + 0..7] (16B contiguous)
//   D^T lane l, reg q: j = jt*16 + (l>>4)*4 + q, r = rb + rt*16 + (l&15)
// 256 threads = 4 waves; wave w owns rows blk*128 + w*32 .. +31; all 128 cols.
// Epilogue bounces through LDS for coalesced bf16 stores.
template <int SRCF32>
__global__ __launch_bounds__(256) void gemm_mfma(
    const void* __restrict__ Ain,          // fp32 or bf16 [n][128]
    const float* __restrict__ W,           // [128][128] row-major (j, k)
    const float* __restrict__ dinv,
    unsigned short* __restrict__ outh,     // bf16 [n][128]
    int n) {
    __shared__ unsigned short Wl[128][136];   // 34816 B
    const int tid = threadIdx.x;
    const int w   = tid >> 6;
    const int l   = tid & 63;
    const int l15 = l & 15;
    const int l4  = l >> 4;

    // stage W fp32 -> bf16 LDS
    #pragma unroll
    for (int rep = 0; rep < 16; ++rep) {
        int f4 = rep * 256 + tid;            // float4 index (4096 total)
        int j  = f4 >> 5;
        int k4 = (f4 & 31) * 4;
        float4 wv = *(const float4*)(W + j * D + k4);
        unsigned int lo = (unsigned int)f2bf(wv.x) | ((unsigned int)f2bf(wv.y) << 16);
        unsigned int hi = (unsigned int)f2bf(wv.z) | ((unsigned int)f2bf(wv.w) << 16);
        *(uint2*)&Wl[j][k4] = make_uint2(lo, hi);
    }
    __syncthreads();

    const int rb = blockIdx.x * 128 + w * 32;

    f32x4 acc[8][2];
    #pragma unroll
    for (int jt = 0; jt < 8; ++jt)
        #pragma unroll
        for (int rt = 0; rt < 2; ++rt)
            acc[jt][rt] = (f32x4){0.f, 0.f, 0.f, 0.f};

    #pragma unroll
    for (int ks = 0; ks < 4; ++ks) {
        const int kk = ks * 32 + l4 * 8;     // this lane's k base
        short8v bfrag[2];
        #pragma unroll
        for (int rt = 0; rt < 2; ++rt) {
            int r = rb + rt * 16 + l15;
            if (SRCF32) {
                const float* af = (const float*)Ain + (size_t)r * D + kk;
                float4 x0, x1;
                if (r < n) { x0 = *(const float4*)af; x1 = *(const float4*)(af + 4); }
                else       { x0 = make_float4(0,0,0,0); x1 = x0; }
                union { short8v v; unsigned short u[8]; } cv;
                cv.u[0] = f2bf(x0.x); cv.u[1] = f2bf(x0.y);
                cv.u[2] = f2bf(x0.z); cv.u[3] = f2bf(x0.w);
                cv.u[4] = f2bf(x1.x); cv.u[5] = f2bf(x1.y);
                cv.u[6] = f2bf(x1.z); cv.u[7] = f2bf(x1.w);
                bfrag[rt] = cv.v;
            } else {
                const unsigned short* ah = (const unsigned short*)Ain + (size_t)r * D + kk;
                if (r < n) bfrag[rt] = *(const short8v*)ah;
                else {
                    union { short8v v; unsigned short u[8]; } z0;
                    #pragma unroll
                    for (int q = 0; q < 8; ++q) z0.u[q] = 0;
                    bfrag[rt] = z0.v;
                }
            }
        }
        #pragma unroll
        for (int jt = 0; jt < 8; ++jt) {
            short8v afrag = *(const short8v*)&Wl[jt * 16 + l15][kk];
            acc[jt][0] = __builtin_amdgcn_mfma_f32_16x16x32_bf16(afrag, bfrag[0], acc[jt][0], 0, 0, 0);
            acc[jt][1] = __builtin_amdgcn_mfma_f32_16x16x32_bf16(afrag, bfrag[1], acc[jt][1], 0, 0, 0);
        }
    }

    // epilogue: dinv scale, bf16, transpose via LDS, coalesced store
    float dv0 = (rb + l15 < n)      ? dinv[rb + l15]      : 0.f;
    float dv1 = (rb + 16 + l15 < n) ? dinv[rb + 16 + l15] : 0.f;

    __syncthreads();                          // done reading W
    unsigned short* eb = &Wl[0][0] + w * (32 * 136);
    #pragma unroll
    for (int jt = 0; jt < 8; ++jt) {
        #pragma unroll
        for (int rt = 0; rt < 2; ++rt) {
            int lr = rt * 16 + l15;
            float s = rt ? dv1 : dv0;
            f32x4 a = acc[jt][rt];
            unsigned int p0 = (unsigned int)f2bf(a[0] * s) | ((unsigned int)f2bf(a[1] * s) << 16);
            unsigned int p1 = (unsigned int)f2bf(a[2] * s) | ((unsigned int)f2bf(a[3] * s) << 16);
            int col = jt * 16 + l4 * 4;
            *(unsigned int*)(eb + lr * 136 + col)     = p0;
            *(unsigned int*)(eb + lr * 136 + col + 2) = p1;
        }
    }
    __syncthreads();
    #pragma unroll
    for (int rep = 0; rep < 8; ++rep) {
        int lr = rep * 4 + l4;
        int c8 = l15 * 8;
        int row = rb + lr;
        if (row < n)
            *(uint4*)(outh + (size_t)row * D + c8) = *(const uint4*)(eb + lr * 136 + c8);
    }
}

// ---------------------------------------------------------------------------
// Gather-aggregation over pre-scaled bf16 rows xh (already scaled by dinv[src]).
//   sum = xh[i] + sum_{r in in(i)} xh[r];  val = dinv[i]*sum
// EPI 0: out fp32 = val + bias             (final output + b2)
// EPI 1: out bf16 = elu(val + table[t[i]]) (h1 path, feeds GEMM2)
template <int EPI>
__global__ __launch_bounds__(256) void gather_bf16(
    const unsigned short* __restrict__ xh, const float* __restrict__ dinv,
    const int* __restrict__ rowptr, const int* __restrict__ csr,
    const float* __restrict__ table, const int* __restrict__ tvec,
    const float* __restrict__ bias,
    void* __restrict__ dst, int n) {
    int wid = (blockIdx.x * 256 + threadIdx.x) >> 6;
    if (wid >= n) return;
    int lane = threadIdx.x & 63;
    const int lo = lane * 2;

    float di = dinv[wid];
    float2 ep;
    if (EPI == 0) {
        ep = *(const float2*)(bias + lo);
    } else {
        int tv = tvec[wid];
        ep = *(const float2*)(table + (size_t)tv * D + lo);
    }

    unsigned int sv = *(const unsigned int*)(xh + (size_t)wid * D + lo);
    float sx = bflo(sv), sy = bfhi(sv);
    int e = rowptr[wid], e1 = rowptr[wid + 1];
    for (; e + 8 <= e1; e += 8) {
        int r0 = csr[e],     r1 = csr[e + 1], r2 = csr[e + 2], r3 = csr[e + 3];
        int r4 = csr[e + 4], r5 = csr[e + 5], r6 = csr[e + 6], r7 = csr[e + 7];
        unsigned int u0 = *(const unsigned int*)(xh + (size_t)r0 * D + lo);
        unsigned int u1 = *(const unsigned int*)(xh + (size_t)r1 * D + lo);
        unsigned int u2 = *(const unsigned int*)(xh + (size_t)r2 * D + lo);
        unsigned int u3 = *(const unsigned int*)(xh + (size_t)r3 * D + lo);
        unsigned int u4 = *(const unsigned int*)(xh + (size_t)r4 * D + lo);
        unsigned int u5 = *(const unsigned int*)(xh + (size_t)r5 * D + lo);
        unsigned int u6 = *(const unsigned int*)(xh + (size_t)r6 * D + lo);
        unsigned int u7 = *(const unsigned int*)(xh + (size_t)r7 * D + lo);
        sx += ((bflo(u0) + bflo(u1)) + (bflo(u2) + bflo(u3)))
            + ((bflo(u4) + bflo(u5)) + (bflo(u6) + bflo(u7)));
        sy += ((bfhi(u0) + bfhi(u1)) + (bfhi(u2) + bfhi(u3)))
            + ((bfhi(u4) + bfhi(u5)) + (bfhi(u6) + bfhi(u7)));
    }
    for (; e < e1; ++e) {
        int r0 = csr[e];
        unsigned int u0 = *(const unsigned int*)(xh + (size_t)r0 * D + lo);
        sx += bflo(u0);
        sy += bfhi(u0);
    }

    float ox = di * sx + ep.x;
    float oy = di * sy + ep.y;
    if (EPI == 0) {
        *(float2*)((float*)dst + (size_t)wid * D + lo) = make_float2(ox, oy);
    } else {
        ox = elu1(ox); oy = elu1(oy);
        unsigned int p = (unsigned int)f2bf(ox) | ((unsigned int)f2bf(oy) << 16);
        *(unsigned int*)((unsigned short*)dst + (size_t)wid * D + lo) = p;
    }
}

// ---------------------------------------------------------------------------
extern "C" void kernel_launch(void* const* d_in, const int* in_sizes, int n_in,
                              void* d_out, int out_size, void* d_ws, size_t ws_size,
                              hipStream_t stream) {
    const float* z   = (const float*)d_in[0];
    const int*   ep  = (const int*)d_in[1];
    const int*   t   = (const int*)d_in[2];
    const float* Wt1 = (const float*)d_in[3];
    const float* bt1 = (const float*)d_in[4];
    const float* Wt2 = (const float*)d_in[5];
    const float* bt2 = (const float*)d_in[6];
    const float* W1  = (const float*)d_in[7];
    const float* b1  = (const float*)d_in[8];
    const float* W2  = (const float*)d_in[9];
    const float* b2  = (const float*)d_in[10];
    float* out = (float*)d_out;

    const int N = in_sizes[0] / D;     // 50000
    const int E = in_sizes[1] / 2;     // 640000
    const int NT = 1000;               // distinct t values

    size_t off = 0;
    auto carve = [&](size_t nbytes) -> void* {
        void* p = (void*)((char*)d_ws + off);
        off += (nbytes + 255) & ~(size_t)255;
        return p;
    };
    int*   flag   = (int*)carve(256);
    int*   deg    = (int*)carve((size_t)N * 4);
    int*   cursor = (int*)carve((size_t)N * 4);
    int*   rowptr = (int*)carve((size_t)(N + 1) * 4);
    float* dinv   = (float*)carve((size_t)N * 4);
    int*   csr    = (int*)carve((size_t)E * 4);
    float* WTt2   = (float*)carve((size_t)16384 * 4);
    float* G      = (float*)carve((size_t)NT * D * 4);
    float* table  = (float*)carve((size_t)NT * D * 4);
    unsigned short* xwh  = (unsigned short*)carve((size_t)N * D * 2);
    unsigned short* acch = (unsigned short*)carve((size_t)N * D * 2);
    (void)ws_size; (void)n_in; (void)out_size;

    hipMemsetAsync(deg, 0, (size_t)N * 4, stream);
    hipMemsetAsync(cursor, 0, (size_t)N * 4, stream);

    detect64_kernel<<<1, 256, 0, stream>>>(ep, flag, 2000);
    transpose_wt2_kernel<<<64, 256, 0, stream>>>(Wt2, WTt2);
    gelu_table_kernel<<<(NT * D + 255) / 256, 256, 0, stream>>>(Wt1, bt1, G, NT);
    count_deg_kernel<<<(E + 255) / 256, 256, 0, stream>>>(ep, flag, deg, E);
    scan_exclusive_kernel<<<1, 1024, 0, stream>>>(deg, rowptr, N);
    dinv_kernel<<<(N + 255) / 256, 256, 0, stream>>>(deg, dinv, N);
    fill_csr_kernel<<<(E + 255) / 256, 256, 0, stream>>>(ep, flag, rowptr, cursor, csr, E);

    // t_emb table: table = G @ Wt2.T + bt2 + b1   (1000 rows, fp32)
    dim3 gemm_grid_t((NT + 127) / 128, 2);
    gemm128_v3<<<gemm_grid_t, 256, 0, stream>>>(G, WTt2, bt2, b1, table, NT);

    int mfma_blocks = (N + 127) / 128;
    // xwh = bf16( dinv * (z @ W1.T) )
    gemm_mfma<1><<<mfma_blocks, 256, 0, stream>>>(z, W1, dinv, xwh, N);
    // acch = bf16( elu( dinv*(sum of xwh rows) + table[t] ) )
    gather_bf16<1><<<(N * 64 + 255) / 256, 256, 0, stream>>>(
        xwh, dinv, rowptr, csr, table, t, nullptr, acch, N);
    // xwh = bf16( dinv * (acch @ W2.T) )
    gemm_mfma<0><<<mfma_blocks, 256, 0, stream>>>(acch, W2, dinv, xwh, N);
    // out = dinv*(sum of xwh rows) + b2   (fp32)
    gather_bf16<0><<<(N * 64 + 255) / 256, 256, 0, stream>>>(
        xwh, dinv, rowptr, csr, nullptr, nullptr, b2, out, N);
}

// Round 6
// 209.610 us; speedup vs baseline: 2.1660x; 1.1915x over previous
//
#include <hip/hip_runtime.h>
#include <hip/hip_bf16.h>
#include <math.h>

#define D 128

typedef __attribute__((ext_vector_type(8))) short short8v;
typedef __attribute__((ext_vector_type(4))) float f32x4;

__device__ __forceinline__ float gelu_exact(float x) {
    return 0.5f * x * (1.0f + erff(x * 0.70710678118654752440f));
}
__device__ __forceinline__ float elu1(float x) {
    return x > 0.f ? x : expm1f(x);
}
__device__ __forceinline__ unsigned short f2bf(float f) {   // RNE fp32->bf16 bits
    unsigned int u = __float_as_uint(f);
    u += 0x7fffu + ((u >> 16) & 1u);
    return (unsigned short)(u >> 16);
}
__device__ __forceinline__ float bflo(unsigned int u) {     // low bf16 of packed pair
    return __uint_as_float(u << 16);
}
__device__ __forceinline__ float bfhi(unsigned int u) {     // high bf16 of packed pair
    return __uint_as_float(u & 0xffff0000u);
}

// ---------------------------------------------------------------------------
__global__ void detect64_kernel(const int* __restrict__ p, int* __restrict__ flag, int npairs) {
    __shared__ int any;
    if (threadIdx.x == 0) any = 0;
    __syncthreads();
    for (int i = threadIdx.x; i < npairs; i += blockDim.x) {
        if (p[2 * i + 1] != 0) any = 1;   // benign race
    }
    __syncthreads();
    if (threadIdx.x == 0) flag[0] = any ? 0 : 1;
}

// ---------------------------------------------------------------------------
__global__ void count_deg_kernel(const int* __restrict__ ep, const int* __restrict__ flag,
                                 int* __restrict__ deg, int E) {
    int e = blockIdx.x * blockDim.x + threadIdx.x;
    if (e >= E) return;
    int mode = flag[0];
    int c = mode ? ep[2 * (E + e)] : ep[E + e];
    atomicAdd(&deg[c], 1);
}

// ---------------------------------------------------------------------------
// Wave-aggregated bucket allocator: start[i] = disjoint contiguous range of
// length deg[i]. Order across waves is arbitrary (irrelevant for correctness):
// per-wave shuffle scan, one atomicAdd per wave (782 total).
__global__ void alloc_start_kernel(const int* __restrict__ deg, int* __restrict__ start,
                                   int* __restrict__ counter, int n) {
    int i = blockIdx.x * blockDim.x + threadIdx.x;
    int lane = threadIdx.x & 63;
    int v = (i < n) ? deg[i] : 0;
    int s = v;
    #pragma unroll
    for (int off = 1; off < 64; off <<= 1) {
        int t = __shfl_up(s, off);
        if (lane >= off) s += t;
    }
    int total = __shfl(s, 63);
    int base = 0;
    if (lane == 63) base = atomicAdd(counter, total);
    base = __shfl(base, 63);
    if (i < n) start[i] = base + s - v;
}

// ---------------------------------------------------------------------------
__global__ void dinv_kernel(const int* __restrict__ deg, float* __restrict__ dinv, int n) {
    int i = blockIdx.x * blockDim.x + threadIdx.x;
    if (i >= n) return;
    dinv[i] = 1.0f / sqrtf((float)(deg[i] + 1));   // +1 self loop
}

// ---------------------------------------------------------------------------
__global__ void fill_csr_kernel(const int* __restrict__ ep, const int* __restrict__ flag,
                                const int* __restrict__ start, int* __restrict__ cursor,
                                int* __restrict__ csr, int E) {
    int e = blockIdx.x * blockDim.x + threadIdx.x;
    if (e >= E) return;
    int mode = flag[0];
    int r = mode ? ep[2 * e] : ep[e];
    int c = mode ? ep[2 * (E + e)] : ep[E + e];
    int pos = atomicAdd(&cursor[c], 1);
    csr[start[c] + pos] = r;
}

// ---------------------------------------------------------------------------
// Transpose Wt2 (k-major) for the fp32 table GEMM.
__global__ void transpose_wt2_kernel(const float* __restrict__ Wt2, float* __restrict__ WT) {
    int idx = blockIdx.x * blockDim.x + threadIdx.x;   // 0..16384
    if (idx >= 16384) return;
    int j = idx >> 7, k = idx & 127;
    WT[k * 128 + j] = Wt2[idx];
}

// ---------------------------------------------------------------------------
// G[v][k] = gelu(v * wt1[k] + bt1[k])
__global__ void gelu_table_kernel(const float* __restrict__ wt1, const float* __restrict__ bt1,
                                  float* __restrict__ G, int nt) {
    int idx = blockIdx.x * blockDim.x + threadIdx.x;
    if (idx >= nt * D) return;
    int v = idx >> 7, k = idx & 127;
    G[idx] = gelu_exact(fmaf((float)v, wt1[k], bt1[k]));
}

// ---------------------------------------------------------------------------
// fp32 GEMM (table path only, 1000 rows): out = A @ WT + bias + bias2
__global__ __launch_bounds__(256) void gemm128_v3(
    const float* __restrict__ Ain,
    const float* __restrict__ WT,
    const float* __restrict__ bias, const float* __restrict__ bias2,
    float* __restrict__ out, int n) {
    __shared__ float Wsh[128][68];
    const int tid = threadIdx.x;
    const int r0 = blockIdx.x * 128;
    const int jb = blockIdx.y * 64;

    #pragma unroll
    for (int rep = 0; rep < 8; ++rep) {
        int flat = rep * 256 + tid;
        int k = flat >> 4;
        int jj = (flat & 15) * 4;
        *(float4*)&Wsh[k][jj] = *(const float4*)(WT + k * D + jb + jj);
    }
    __syncthreads();

    const int tx = tid & 7, ty = tid >> 3;
    const int rbase = r0 + ty * 4;
    const int jcol = tx * 8;

    float acc[4][8];
    #pragma unroll
    for (int i = 0; i < 4; ++i)
        #pragma unroll
        for (int j = 0; j < 8; ++j) acc[i][j] = 0.f;

    #pragma unroll 2
    for (int k0 = 0; k0 < 128; k0 += 4) {
        float4 a[4];
        #pragma unroll
        for (int i = 0; i < 4; ++i) {
            int rr = rbase + i;
            a[i] = (rr < n) ? *(const float4*)(Ain + (size_t)rr * D + k0)
                            : make_float4(0.f, 0.f, 0.f, 0.f);
        }
        float4 wv[4][2];
        #pragma unroll
        for (int kk = 0; kk < 4; ++kk) {
            wv[kk][0] = *(const float4*)&Wsh[k0 + kk][jcol];
            wv[kk][1] = *(const float4*)&Wsh[k0 + kk][jcol + 4];
        }
        #pragma unroll
        for (int i = 0; i < 4; ++i) {
            float av[4] = {a[i].x, a[i].y, a[i].z, a[i].w};
            #pragma unroll
            for (int kk = 0; kk < 4; ++kk) {
                acc[i][0] = fmaf(av[kk], wv[kk][0].x, acc[i][0]);
                acc[i][1] = fmaf(av[kk], wv[kk][0].y, acc[i][1]);
                acc[i][2] = fmaf(av[kk], wv[kk][0].z, acc[i][2]);
                acc[i][3] = fmaf(av[kk], wv[kk][0].w, acc[i][3]);
                acc[i][4] = fmaf(av[kk], wv[kk][1].x, acc[i][4]);
                acc[i][5] = fmaf(av[kk], wv[kk][1].y, acc[i][5]);
                acc[i][6] = fmaf(av[kk], wv[kk][1].z, acc[i][6]);
                acc[i][7] = fmaf(av[kk], wv[kk][1].w, acc[i][7]);
            }
        }
    }

    float4 ba = *(const float4*)(bias + jb + jcol);
    float4 bb = *(const float4*)(bias2 + jb + jcol);
    float4 badd0 = make_float4(ba.x + bb.x, ba.y + bb.y, ba.z + bb.z, ba.w + bb.w);
    ba = *(const float4*)(bias + jb + jcol + 4);
    bb = *(const float4*)(bias2 + jb + jcol + 4);
    float4 badd1 = make_float4(ba.x + bb.x, ba.y + bb.y, ba.z + bb.z, ba.w + bb.w);
    #pragma unroll
    for (int i = 0; i < 4; ++i) {
        int rr = rbase + i;
        if (rr < n) {
            float4 o0, o1;
            o0.x = acc[i][0] + badd0.x; o0.y = acc[i][1] + badd0.y;
            o0.z = acc[i][2] + badd0.z; o0.w = acc[i][3] + badd0.w;
            o1.x = acc[i][4] + badd1.x; o1.y = acc[i][5] + badd1.y;
            o1.z = acc[i][6] + badd1.z; o1.w = acc[i][7] + badd1.w;
            *(float4*)(out + (size_t)rr * D + jb + jcol) = o0;
            *(float4*)(out + (size_t)rr * D + jb + jcol + 4) = o1;
        }
    }
}

// ---------------------------------------------------------------------------
// bf16 MFMA GEMM: outh[r][j] = bf16( dinv[r] * sum_k A[r][k] * W[j][k] )
// Swapped operands: D^T = W · A^T  (mfma 16x16x32 bf16).
template <int SRCF32>
__global__ __launch_bounds__(256) void gemm_mfma(
    const void* __restrict__ Ain,          // fp32 or bf16 [n][128]
    const float* __restrict__ W,           // [128][128] row-major (j, k)
    const float* __restrict__ dinv,
    unsigned short* __restrict__ outh,     // bf16 [n][128]
    int n) {
    __shared__ unsigned short Wl[128][136];   // 34816 B
    const int tid = threadIdx.x;
    const int w   = tid >> 6;
    const int l   = tid & 63;
    const int l15 = l & 15;
    const int l4  = l >> 4;

    // stage W fp32 -> bf16 LDS
    #pragma unroll
    for (int rep = 0; rep < 16; ++rep) {
        int f4 = rep * 256 + tid;            // float4 index (4096 total)
        int j  = f4 >> 5;
        int k4 = (f4 & 31) * 4;
        float4 wv = *(const float4*)(W + j * D + k4);
        unsigned int lo = (unsigned int)f2bf(wv.x) | ((unsigned int)f2bf(wv.y) << 16);
        unsigned int hi = (unsigned int)f2bf(wv.z) | ((unsigned int)f2bf(wv.w) << 16);
        *(uint2*)&Wl[j][k4] = make_uint2(lo, hi);
    }
    __syncthreads();

    const int rb = blockIdx.x * 128 + w * 32;

    f32x4 acc[8][2];
    #pragma unroll
    for (int jt = 0; jt < 8; ++jt)
        #pragma unroll
        for (int rt = 0; rt < 2; ++rt)
            acc[jt][rt] = (f32x4){0.f, 0.f, 0.f, 0.f};

    #pragma unroll
    for (int ks = 0; ks < 4; ++ks) {
        const int kk = ks * 32 + l4 * 8;     // this lane's k base
        short8v bfrag[2];
        #pragma unroll
        for (int rt = 0; rt < 2; ++rt) {
            int r = rb + rt * 16 + l15;
            if (SRCF32) {
                const float* af = (const float*)Ain + (size_t)r * D + kk;
                float4 x0, x1;
                if (r < n) { x0 = *(const float4*)af; x1 = *(const float4*)(af + 4); }
                else       { x0 = make_float4(0,0,0,0); x1 = x0; }
                union { short8v v; unsigned short u[8]; } cv;
                cv.u[0] = f2bf(x0.x); cv.u[1] = f2bf(x0.y);
                cv.u[2] = f2bf(x0.z); cv.u[3] = f2bf(x0.w);
                cv.u[4] = f2bf(x1.x); cv.u[5] = f2bf(x1.y);
                cv.u[6] = f2bf(x1.z); cv.u[7] = f2bf(x1.w);
                bfrag[rt] = cv.v;
            } else {
                const unsigned short* ah = (const unsigned short*)Ain + (size_t)r * D + kk;
                if (r < n) bfrag[rt] = *(const short8v*)ah;
                else {
                    union { short8v v; unsigned short u[8]; } z0;
                    #pragma unroll
                    for (int q = 0; q < 8; ++q) z0.u[q] = 0;
                    bfrag[rt] = z0.v;
                }
            }
        }
        #pragma unroll
        for (int jt = 0; jt < 8; ++jt) {
            short8v afrag = *(const short8v*)&Wl[jt * 16 + l15][kk];
            acc[jt][0] = __builtin_amdgcn_mfma_f32_16x16x32_bf16(afrag, bfrag[0], acc[jt][0], 0, 0, 0);
            acc[jt][1] = __builtin_amdgcn_mfma_f32_16x16x32_bf16(afrag, bfrag[1], acc[jt][1], 0, 0, 0);
        }
    }

    // epilogue: dinv scale, bf16, transpose via LDS, coalesced store
    float dv0 = (rb + l15 < n)      ? dinv[rb + l15]      : 0.f;
    float dv1 = (rb + 16 + l15 < n) ? dinv[rb + 16 + l15] : 0.f;

    __syncthreads();                          // done reading W
    unsigned short* eb = &Wl[0][0] + w * (32 * 136);
    #pragma unroll
    for (int jt = 0; jt < 8; ++jt) {
        #pragma unroll
        for (int rt = 0; rt < 2; ++rt) {
            int lr = rt * 16 + l15;
            float s = rt ? dv1 : dv0;
            f32x4 a = acc[jt][rt];
            unsigned int p0 = (unsigned int)f2bf(a[0] * s) | ((unsigned int)f2bf(a[1] * s) << 16);
            unsigned int p1 = (unsigned int)f2bf(a[2] * s) | ((unsigned int)f2bf(a[3] * s) << 16);
            int col = jt * 16 + l4 * 4;
            *(unsigned int*)(eb + lr * 136 + col)     = p0;
            *(unsigned int*)(eb + lr * 136 + col + 2) = p1;
        }
    }
    __syncthreads();
    #pragma unroll
    for (int rep = 0; rep < 8; ++rep) {
        int lr = rep * 4 + l4;
        int c8 = l15 * 8;
        int row = rb + lr;
        if (row < n)
            *(uint4*)(outh + (size_t)row * D + c8) = *(const uint4*)(eb + lr * 136 + c8);
    }
}

// ---------------------------------------------------------------------------
// Gather-aggregation over pre-scaled bf16 rows xh (already scaled by dinv[src]).
//   sum = xh[i] + sum_{r in in(i)} xh[r];  val = dinv[i]*sum
// EPI 0: out fp32 = val + bias             (final output + b2)
// EPI 1: out bf16 = elu(val + table[t[i]]) (h1 path, feeds GEMM2)
template <int EPI>
__global__ __launch_bounds__(256) void gather_bf16(
    const unsigned short* __restrict__ xh, const float* __restrict__ dinv,
    const int* __restrict__ start, const int* __restrict__ deg,
    const int* __restrict__ csr,
    const float* __restrict__ table, const int* __restrict__ tvec,
    const float* __restrict__ bias,
    void* __restrict__ dst, int n) {
    int wid = (blockIdx.x * 256 + threadIdx.x) >> 6;
    if (wid >= n) return;
    int lane = threadIdx.x & 63;
    const int lo = lane * 2;

    float di = dinv[wid];
    float2 ep;
    if (EPI == 0) {
        ep = *(const float2*)(bias + lo);
    } else {
        int tv = tvec[wid];
        ep = *(const float2*)(table + (size_t)tv * D + lo);
    }

    unsigned int sv = *(const unsigned int*)(xh + (size_t)wid * D + lo);
    float sx = bflo(sv), sy = bfhi(sv);
    int e = start[wid], e1 = e + deg[wid];
    for (; e + 8 <= e1; e += 8) {
        int r0 = csr[e],     r1 = csr[e + 1], r2 = csr[e + 2], r3 = csr[e + 3];
        int r4 = csr[e + 4], r5 = csr[e + 5], r6 = csr[e + 6], r7 = csr[e + 7];
        unsigned int u0 = *(const unsigned int*)(xh + (size_t)r0 * D + lo);
        unsigned int u1 = *(const unsigned int*)(xh + (size_t)r1 * D + lo);
        unsigned int u2 = *(const unsigned int*)(xh + (size_t)r2 * D + lo);
        unsigned int u3 = *(const unsigned int*)(xh + (size_t)r3 * D + lo);
        unsigned int u4 = *(const unsigned int*)(xh + (size_t)r4 * D + lo);
        unsigned int u5 = *(const unsigned int*)(xh + (size_t)r5 * D + lo);
        unsigned int u6 = *(const unsigned int*)(xh + (size_t)r6 * D + lo);
        unsigned int u7 = *(const unsigned int*)(xh + (size_t)r7 * D + lo);
        sx += ((bflo(u0) + bflo(u1)) + (bflo(u2) + bflo(u3)))
            + ((bflo(u4) + bflo(u5)) + (bflo(u6) + bflo(u7)));
        sy += ((bfhi(u0) + bfhi(u1)) + (bfhi(u2) + bfhi(u3)))
            + ((bfhi(u4) + bfhi(u5)) + (bfhi(u6) + bfhi(u7)));
    }
    for (; e < e1; ++e) {
        int r0 = csr[e];
        unsigned int u0 = *(const unsigned int*)(xh + (size_t)r0 * D + lo);
        sx += bflo(u0);
        sy += bfhi(u0);
    }

    float ox = di * sx + ep.x;
    float oy = di * sy + ep.y;
    if (EPI == 0) {
        *(float2*)((float*)dst + (size_t)wid * D + lo) = make_float2(ox, oy);
    } else {
        ox = elu1(ox); oy = elu1(oy);
        unsigned int p = (unsigned int)f2bf(ox) | ((unsigned int)f2bf(oy) << 16);
        *(unsigned int*)((unsigned short*)dst + (size_t)wid * D + lo) = p;
    }
}

// ---------------------------------------------------------------------------
extern "C" void kernel_launch(void* const* d_in, const int* in_sizes, int n_in,
                              void* d_out, int out_size, void* d_ws, size_t ws_size,
                              hipStream_t stream) {
    const float* z   = (const float*)d_in[0];
    const int*   ep  = (const int*)d_in[1];
    const int*   t   = (const int*)d_in[2];
    const float* Wt1 = (const float*)d_in[3];
    const float* bt1 = (const float*)d_in[4];
    const float* Wt2 = (const float*)d_in[5];
    const float* bt2 = (const float*)d_in[6];
    const float* W1  = (const float*)d_in[7];
    const float* b1  = (const float*)d_in[8];
    const float* W2  = (const float*)d_in[9];
    const float* b2  = (const float*)d_in[10];
    float* out = (float*)d_out;

    const int N = in_sizes[0] / D;     // 50000
    const int E = in_sizes[1] / 2;     // 640000
    const int NT = 1000;               // distinct t values

    size_t off = 0;
    auto carve = [&](size_t nbytes) -> void* {
        void* p = (void*)((char*)d_ws + off);
        off += (nbytes + 255) & ~(size_t)255;
        return p;
    };
    int*   flag   = (int*)carve(256);
    // deg / cursor / counter are contiguous -> one memset covers all three
    char*  zero_base = (char*)d_ws + off;
    int*   deg    = (int*)carve((size_t)N * 4);
    int*   cursor = (int*)carve((size_t)N * 4);
    int*   counter= (int*)carve(256);
    size_t zero_len = (size_t)((char*)d_ws + off - zero_base);
    int*   start  = (int*)carve((size_t)N * 4);
    float* dinv   = (float*)carve((size_t)N * 4);
    int*   csr    = (int*)carve((size_t)E * 4);
    float* WTt2   = (float*)carve((size_t)16384 * 4);
    float* G      = (float*)carve((size_t)NT * D * 4);
    float* table  = (float*)carve((size_t)NT * D * 4);
    unsigned short* xwh  = (unsigned short*)carve((size_t)N * D * 2);
    unsigned short* acch = (unsigned short*)carve((size_t)N * D * 2);
    (void)ws_size; (void)n_in; (void)out_size;

    hipMemsetAsync(zero_base, 0, zero_len, stream);

    detect64_kernel<<<1, 256, 0, stream>>>(ep, flag, 2000);
    transpose_wt2_kernel<<<64, 256, 0, stream>>>(Wt2, WTt2);
    gelu_table_kernel<<<(NT * D + 255) / 256, 256, 0, stream>>>(Wt1, bt1, G, NT);
    count_deg_kernel<<<(E + 255) / 256, 256, 0, stream>>>(ep, flag, deg, E);
    alloc_start_kernel<<<(N + 255) / 256, 256, 0, stream>>>(deg, start, counter, N);
    dinv_kernel<<<(N + 255) / 256, 256, 0, stream>>>(deg, dinv, N);
    fill_csr_kernel<<<(E + 255) / 256, 256, 0, stream>>>(ep, flag, start, cursor, csr, E);

    // t_emb table: table = G @ Wt2.T + bt2 + b1   (1000 rows, fp32)
    dim3 gemm_grid_t((NT + 127) / 128, 2);
    gemm128_v3<<<gemm_grid_t, 256, 0, stream>>>(G, WTt2, bt2, b1, table, NT);

    int mfma_blocks = (N + 127) / 128;
    // xwh = bf16( dinv * (z @ W1.T) )
    gemm_mfma<1><<<mfma_blocks, 256, 0, stream>>>(z, W1, dinv, xwh, N);
    // acch = bf16( elu( dinv*(sum of xwh rows) + table[t] ) )
    gather_bf16<1><<<(N * 64 + 255) / 256, 256, 0, stream>>>(
        xwh, dinv, start, deg, csr, table, t, nullptr, acch, N);
    // xwh = bf16( dinv * (acch @ W2.T) )
    gemm_mfma<0><<<mfma_blocks, 256, 0, stream>>>(acch, W2, dinv, xwh, N);
    // out = dinv*(sum of xwh rows) + b2   (fp32)
    gather_bf16<0><<<(N * 64 + 255) / 256, 256, 0, stream>>>(
        xwh, dinv, start, deg, csr, nullptr, nullptr, b2, out, N);
}

// Round 7
// 202.786 us; speedup vs baseline: 2.2389x; 1.0337x over previous
//
#include <hip/hip_runtime.h>
#include <hip/hip_bf16.h>
#include <math.h>

#define D 128

typedef __attribute__((ext_vector_type(8))) short short8v;
typedef __attribute__((ext_vector_type(4))) float f32x4;

__device__ __forceinline__ float gelu_exact(float x) {
    return 0.5f * x * (1.0f + erff(x * 0.70710678118654752440f));
}
__device__ __forceinline__ float elu1(float x) {
    return x > 0.f ? x : expm1f(x);
}
__device__ __forceinline__ unsigned short f2bf(float f) {   // RNE fp32->bf16 bits
    unsigned int u = __float_as_uint(f);
    u += 0x7fffu + ((u >> 16) & 1u);
    return (unsigned short)(u >> 16);
}
__device__ __forceinline__ float bflo(unsigned int u) {     // low bf16 of packed pair
    return __uint_as_float(u << 16);
}
__device__ __forceinline__ float bfhi(unsigned int u) {     // high bf16 of packed pair
    return __uint_as_float(u & 0xffff0000u);
}

// ---------------------------------------------------------------------------
__global__ void zero_kernel(int* __restrict__ p, int n) {
    int i = blockIdx.x * blockDim.x + threadIdx.x;
    if (i < n) p[i] = 0;
}

// ---------------------------------------------------------------------------
// Fused prep: block 0 detects int64-vs-int32 edge layout; all blocks also
// cover Wt2 transpose (16384) and the gelu table G (nt*128).
__global__ void prep_kernel(const int* __restrict__ ep, int* __restrict__ flag,
                            const float* __restrict__ Wt2, float* __restrict__ WT,
                            const float* __restrict__ wt1, const float* __restrict__ bt1,
                            float* __restrict__ G, int nt) {
    if (blockIdx.x == 0) {
        __shared__ int any;
        if (threadIdx.x == 0) any = 0;
        __syncthreads();
        for (int i = threadIdx.x; i < 2000; i += 256) {
            if (ep[2 * i + 1] != 0) any = 1;   // benign race
        }
        __syncthreads();
        if (threadIdx.x == 0) flag[0] = any ? 0 : 1;
    }
    int idx = blockIdx.x * blockDim.x + threadIdx.x;
    if (idx < 16384) {
        int j = idx >> 7, k = idx & 127;
        WT[k * 128 + j] = Wt2[idx];
    } else if (idx < 16384 + nt * D) {
        int w = idx - 16384;
        int v = w >> 7, k = w & 127;
        G[w] = gelu_exact(fmaf((float)v, wt1[k], bt1[k]));
    }
}

// ---------------------------------------------------------------------------
__global__ void count_deg_kernel(const int* __restrict__ ep, const int* __restrict__ flag,
                                 int* __restrict__ deg, int E) {
    int e = blockIdx.x * blockDim.x + threadIdx.x;
    if (e >= E) return;
    int mode = flag[0];
    int c = mode ? ep[2 * (E + e)] : ep[E + e];
    atomicAdd(&deg[c], 1);
}

// ---------------------------------------------------------------------------
// Wave-aggregated bucket allocator + dinv. endp[i] = bucket start (becomes
// bucket END after fill_csr bumps it). One atomicAdd per wave.
__global__ void alloc_start_kernel(const int* __restrict__ deg, int* __restrict__ endp,
                                   float* __restrict__ dinv, int* __restrict__ counter, int n) {
    int i = blockIdx.x * blockDim.x + threadIdx.x;
    int lane = threadIdx.x & 63;
    int v = (i < n) ? deg[i] : 0;
    int s = v;
    #pragma unroll
    for (int off = 1; off < 64; off <<= 1) {
        int t = __shfl_up(s, off);
        if (lane >= off) s += t;
    }
    int total = __shfl(s, 63);
    int base = 0;
    if (lane == 63) base = atomicAdd(counter, total);
    base = __shfl(base, 63);
    if (i < n) {
        endp[i] = base + s - v;
        dinv[i] = 1.0f / sqrtf((float)(v + 1));   // +1 self loop
    }
}

// ---------------------------------------------------------------------------
__global__ void fill_csr_kernel(const int* __restrict__ ep, const int* __restrict__ flag,
                                int* __restrict__ endp, int* __restrict__ csr, int E) {
    int e = blockIdx.x * blockDim.x + threadIdx.x;
    if (e >= E) return;
    int mode = flag[0];
    int r = mode ? ep[2 * e] : ep[e];
    int c = mode ? ep[2 * (E + e)] : ep[E + e];
    int pos = atomicAdd(&endp[c], 1);
    csr[pos] = r;
}

// ---------------------------------------------------------------------------
// fp32 GEMM (table path only, 1000 rows): out = A @ WT + bias + bias2
__global__ __launch_bounds__(256) void gemm128_v3(
    const float* __restrict__ Ain,
    const float* __restrict__ WT,
    const float* __restrict__ bias, const float* __restrict__ bias2,
    float* __restrict__ out, int n) {
    __shared__ float Wsh[128][68];
    const int tid = threadIdx.x;
    const int r0 = blockIdx.x * 128;
    const int jb = blockIdx.y * 64;

    #pragma unroll
    for (int rep = 0; rep < 8; ++rep) {
        int flat = rep * 256 + tid;
        int k = flat >> 4;
        int jj = (flat & 15) * 4;
        *(float4*)&Wsh[k][jj] = *(const float4*)(WT + k * D + jb + jj);
    }
    __syncthreads();

    const int tx = tid & 7, ty = tid >> 3;
    const int rbase = r0 + ty * 4;
    const int jcol = tx * 8;

    float acc[4][8];
    #pragma unroll
    for (int i = 0; i < 4; ++i)
        #pragma unroll
        for (int j = 0; j < 8; ++j) acc[i][j] = 0.f;

    #pragma unroll 2
    for (int k0 = 0; k0 < 128; k0 += 4) {
        float4 a[4];
        #pragma unroll
        for (int i = 0; i < 4; ++i) {
            int rr = rbase + i;
            a[i] = (rr < n) ? *(const float4*)(Ain + (size_t)rr * D + k0)
                            : make_float4(0.f, 0.f, 0.f, 0.f);
        }
        float4 wv[4][2];
        #pragma unroll
        for (int kk = 0; kk < 4; ++kk) {
            wv[kk][0] = *(const float4*)&Wsh[k0 + kk][jcol];
            wv[kk][1] = *(const float4*)&Wsh[k0 + kk][jcol + 4];
        }
        #pragma unroll
        for (int i = 0; i < 4; ++i) {
            float av[4] = {a[i].x, a[i].y, a[i].z, a[i].w};
            #pragma unroll
            for (int kk = 0; kk < 4; ++kk) {
                acc[i][0] = fmaf(av[kk], wv[kk][0].x, acc[i][0]);
                acc[i][1] = fmaf(av[kk], wv[kk][0].y, acc[i][1]);
                acc[i][2] = fmaf(av[kk], wv[kk][0].z, acc[i][2]);
                acc[i][3] = fmaf(av[kk], wv[kk][0].w, acc[i][3]);
                acc[i][4] = fmaf(av[kk], wv[kk][1].x, acc[i][4]);
                acc[i][5] = fmaf(av[kk], wv[kk][1].y, acc[i][5]);
                acc[i][6] = fmaf(av[kk], wv[kk][1].z, acc[i][6]);
                acc[i][7] = fmaf(av[kk], wv[kk][1].w, acc[i][7]);
            }
        }
    }

    float4 ba = *(const float4*)(bias + jb + jcol);
    float4 bb = *(const float4*)(bias2 + jb + jcol);
    float4 badd0 = make_float4(ba.x + bb.x, ba.y + bb.y, ba.z + bb.z, ba.w + bb.w);
    ba = *(const float4*)(bias + jb + jcol + 4);
    bb = *(const float4*)(bias2 + jb + jcol + 4);
    float4 badd1 = make_float4(ba.x + bb.x, ba.y + bb.y, ba.z + bb.z, ba.w + bb.w);
    #pragma unroll
    for (int i = 0; i < 4; ++i) {
        int rr = rbase + i;
        if (rr < n) {
            float4 o0, o1;
            o0.x = acc[i][0] + badd0.x; o0.y = acc[i][1] + badd0.y;
            o0.z = acc[i][2] + badd0.z; o0.w = acc[i][3] + badd0.w;
            o1.x = acc[i][4] + badd1.x; o1.y = acc[i][5] + badd1.y;
            o1.z = acc[i][6] + badd1.z; o1.w = acc[i][7] + badd1.w;
            *(float4*)(out + (size_t)rr * D + jb + jcol) = o0;
            *(float4*)(out + (size_t)rr * D + jb + jcol + 4) = o1;
        }
    }
}

// ---------------------------------------------------------------------------
// bf16 MFMA GEMM: outh[r][j] = bf16( dinv[r] * sum_k A[r][k] * W[j][k] )
// Swapped operands: D^T = W · A^T  (mfma 16x16x32 bf16).
template <int SRCF32>
__global__ __launch_bounds__(256) void gemm_mfma(
    const void* __restrict__ Ain,          // fp32 or bf16 [n][128]
    const float* __restrict__ W,           // [128][128] row-major (j, k)
    const float* __restrict__ dinv,
    unsigned short* __restrict__ outh,     // bf16 [n][128]
    int n) {
    __shared__ unsigned short Wl[128][136];   // 34816 B
    const int tid = threadIdx.x;
    const int w   = tid >> 6;
    const int l   = tid & 63;
    const int l15 = l & 15;
    const int l4  = l >> 4;

    // stage W fp32 -> bf16 LDS
    #pragma unroll
    for (int rep = 0; rep < 16; ++rep) {
        int f4 = rep * 256 + tid;            // float4 index (4096 total)
        int j  = f4 >> 5;
        int k4 = (f4 & 31) * 4;
        float4 wv = *(const float4*)(W + j * D + k4);
        unsigned int lo = (unsigned int)f2bf(wv.x) | ((unsigned int)f2bf(wv.y) << 16);
        unsigned int hi = (unsigned int)f2bf(wv.z) | ((unsigned int)f2bf(wv.w) << 16);
        *(uint2*)&Wl[j][k4] = make_uint2(lo, hi);
    }
    __syncthreads();

    const int rb = blockIdx.x * 128 + w * 32;

    f32x4 acc[8][2];
    #pragma unroll
    for (int jt = 0; jt < 8; ++jt)
        #pragma unroll
        for (int rt = 0; rt < 2; ++rt)
            acc[jt][rt] = (f32x4){0.f, 0.f, 0.f, 0.f};

    #pragma unroll
    for (int ks = 0; ks < 4; ++ks) {
        const int kk = ks * 32 + l4 * 8;     // this lane's k base
        short8v bfrag[2];
        #pragma unroll
        for (int rt = 0; rt < 2; ++rt) {
            int r = rb + rt * 16 + l15;
            if (SRCF32) {
                const float* af = (const float*)Ain + (size_t)r * D + kk;
                float4 x0, x1;
                if (r < n) { x0 = *(const float4*)af; x1 = *(const float4*)(af + 4); }
                else       { x0 = make_float4(0,0,0,0); x1 = x0; }
                union { short8v v; unsigned short u[8]; } cv;
                cv.u[0] = f2bf(x0.x); cv.u[1] = f2bf(x0.y);
                cv.u[2] = f2bf(x0.z); cv.u[3] = f2bf(x0.w);
                cv.u[4] = f2bf(x1.x); cv.u[5] = f2bf(x1.y);
                cv.u[6] = f2bf(x1.z); cv.u[7] = f2bf(x1.w);
                bfrag[rt] = cv.v;
            } else {
                const unsigned short* ah = (const unsigned short*)Ain + (size_t)r * D + kk;
                if (r < n) bfrag[rt] = *(const short8v*)ah;
                else {
                    union { short8v v; unsigned short u[8]; } z0;
                    #pragma unroll
                    for (int q = 0; q < 8; ++q) z0.u[q] = 0;
                    bfrag[rt] = z0.v;
                }
            }
        }
        #pragma unroll
        for (int jt = 0; jt < 8; ++jt) {
            short8v afrag = *(const short8v*)&Wl[jt * 16 + l15][kk];
            acc[jt][0] = __builtin_amdgcn_mfma_f32_16x16x32_bf16(afrag, bfrag[0], acc[jt][0], 0, 0, 0);
            acc[jt][1] = __builtin_amdgcn_mfma_f32_16x16x32_bf16(afrag, bfrag[1], acc[jt][1], 0, 0, 0);
        }
    }

    // epilogue: dinv scale, bf16, transpose via LDS, coalesced store
    float dv0 = (rb + l15 < n)      ? dinv[rb + l15]      : 0.f;
    float dv1 = (rb + 16 + l15 < n) ? dinv[rb + 16 + l15] : 0.f;

    __syncthreads();                          // done reading W
    unsigned short* eb = &Wl[0][0] + w * (32 * 136);
    #pragma unroll
    for (int jt = 0; jt < 8; ++jt) {
        #pragma unroll
        for (int rt = 0; rt < 2; ++rt) {
            int lr = rt * 16 + l15;
            float s = rt ? dv1 : dv0;
            f32x4 a = acc[jt][rt];
            unsigned int p0 = (unsigned int)f2bf(a[0] * s) | ((unsigned int)f2bf(a[1] * s) << 16);
            unsigned int p1 = (unsigned int)f2bf(a[2] * s) | ((unsigned int)f2bf(a[3] * s) << 16);
            int col = jt * 16 + l4 * 4;
            *(unsigned int*)(eb + lr * 136 + col)     = p0;
            *(unsigned int*)(eb + lr * 136 + col + 2) = p1;
        }
    }
    __syncthreads();
    #pragma unroll
    for (int rep = 0; rep < 8; ++rep) {
        int lr = rep * 4 + l4;
        int c8 = l15 * 8;
        int row = rb + lr;
        if (row < n)
            *(uint4*)(outh + (size_t)row * D + c8) = *(const uint4*)(eb + lr * 136 + c8);
    }
}

// ---------------------------------------------------------------------------
// Gather-aggregation over pre-scaled bf16 rows xh (already scaled by dinv[src]).
//   sum = xh[i] + sum_{r in in(i)} xh[r];  val = dinv[i]*sum
// Bucket i = [endp[i]-deg[i], endp[i]) after fill_csr.
// EPI 0: out fp32 = val + bias             (final output + b2)
// EPI 1: out bf16 = elu(val + table[t[i]]) (h1 path, feeds GEMM2)
template <int EPI>
__global__ __launch_bounds__(256) void gather_bf16(
    const unsigned short* __restrict__ xh, const float* __restrict__ dinv,
    const int* __restrict__ endp, const int* __restrict__ deg,
    const int* __restrict__ csr,
    const float* __restrict__ table, const int* __restrict__ tvec,
    const float* __restrict__ bias,
    void* __restrict__ dst, int n) {
    int wid = (blockIdx.x * 256 + threadIdx.x) >> 6;
    if (wid >= n) return;
    int lane = threadIdx.x & 63;
    const int lo = lane * 2;

    int e1 = endp[wid];
    int dg = deg[wid];
    int e  = e1 - dg;
    float di = dinv[wid];
    float2 ep;
    if (EPI == 0) {
        ep = *(const float2*)(bias + lo);
    } else {
        int tv = tvec[wid];
        ep = *(const float2*)(table + (size_t)tv * D + lo);
    }

    unsigned int sv = *(const unsigned int*)(xh + (size_t)wid * D + lo);
    float sx = bflo(sv), sy = bfhi(sv);
    for (; e + 8 <= e1; e += 8) {
        int r0 = csr[e],     r1 = csr[e + 1], r2 = csr[e + 2], r3 = csr[e + 3];
        int r4 = csr[e + 4], r5 = csr[e + 5], r6 = csr[e + 6], r7 = csr[e + 7];
        unsigned int u0 = *(const unsigned int*)(xh + (size_t)r0 * D + lo);
        unsigned int u1 = *(const unsigned int*)(xh + (size_t)r1 * D + lo);
        unsigned int u2 = *(const unsigned int*)(xh + (size_t)r2 * D + lo);
        unsigned int u3 = *(const unsigned int*)(xh + (size_t)r3 * D + lo);
        unsigned int u4 = *(const unsigned int*)(xh + (size_t)r4 * D + lo);
        unsigned int u5 = *(const unsigned int*)(xh + (size_t)r5 * D + lo);
        unsigned int u6 = *(const unsigned int*)(xh + (size_t)r6 * D + lo);
        unsigned int u7 = *(const unsigned int*)(xh + (size_t)r7 * D + lo);
        sx += ((bflo(u0) + bflo(u1)) + (bflo(u2) + bflo(u3)))
            + ((bflo(u4) + bflo(u5)) + (bflo(u6) + bflo(u7)));
        sy += ((bfhi(u0) + bfhi(u1)) + (bfhi(u2) + bfhi(u3)))
            + ((bfhi(u4) + bfhi(u5)) + (bfhi(u6) + bfhi(u7)));
    }
    for (; e < e1; ++e) {
        int r0 = csr[e];
        unsigned int u0 = *(const unsigned int*)(xh + (size_t)r0 * D + lo);
        sx += bflo(u0);
        sy += bfhi(u0);
    }

    float ox = di * sx + ep.x;
    float oy = di * sy + ep.y;
    if (EPI == 0) {
        *(float2*)((float*)dst + (size_t)wid * D + lo) = make_float2(ox, oy);
    } else {
        ox = elu1(ox); oy = elu1(oy);
        unsigned int p = (unsigned int)f2bf(ox) | ((unsigned int)f2bf(oy) << 16);
        *(unsigned int*)((unsigned short*)dst + (size_t)wid * D + lo) = p;
    }
}

// ---------------------------------------------------------------------------
extern "C" void kernel_launch(void* const* d_in, const int* in_sizes, int n_in,
                              void* d_out, int out_size, void* d_ws, size_t ws_size,
                              hipStream_t stream) {
    const float* z   = (const float*)d_in[0];
    const int*   ep  = (const int*)d_in[1];
    const int*   t   = (const int*)d_in[2];
    const float* Wt1 = (const float*)d_in[3];
    const float* bt1 = (const float*)d_in[4];
    const float* Wt2 = (const float*)d_in[5];
    const float* bt2 = (const float*)d_in[6];
    const float* W1  = (const float*)d_in[7];
    const float* b1  = (const float*)d_in[8];
    const float* W2  = (const float*)d_in[9];
    const float* b2  = (const float*)d_in[10];
    float* out = (float*)d_out;

    const int N = in_sizes[0] / D;     // 50000
    const int E = in_sizes[1] / 2;     // 640000
    const int NT = 1000;               // distinct t values

    size_t off = 0;
    auto carve = [&](size_t nbytes) -> void* {
        void* p = (void*)((char*)d_ws + off);
        off += (nbytes + 255) & ~(size_t)255;
        return p;
    };
    int*   flag   = (int*)carve(256);
    // deg + counter contiguous -> one zero_kernel covers both
    char*  zero_base = (char*)d_ws + off;
    int*   deg    = (int*)carve((size_t)N * 4);
    int*   counter= (int*)carve(256);
    int    nzero  = (int)(((char*)d_ws + off - zero_base) / 4);
    int*   endp   = (int*)carve((size_t)N * 4);
    float* dinv   = (float*)carve((size_t)N * 4);
    int*   csr    = (int*)carve((size_t)E * 4);
    float* WTt2   = (float*)carve((size_t)16384 * 4);
    float* G      = (float*)carve((size_t)NT * D * 4);
    float* table  = (float*)carve((size_t)NT * D * 4);
    unsigned short* xwh  = (unsigned short*)carve((size_t)N * D * 2);
    unsigned short* acch = (unsigned short*)carve((size_t)N * D * 2);
    (void)ws_size; (void)n_in; (void)out_size;

    zero_kernel<<<(nzero + 255) / 256, 256, 0, stream>>>((int*)zero_base, nzero);
    prep_kernel<<<(16384 + NT * D + 255) / 256, 256, 0, stream>>>(
        ep, flag, Wt2, WTt2, Wt1, bt1, G, NT);
    count_deg_kernel<<<(E + 255) / 256, 256, 0, stream>>>(ep, flag, deg, E);
    alloc_start_kernel<<<(N + 255) / 256, 256, 0, stream>>>(deg, endp, dinv, counter, N);
    fill_csr_kernel<<<(E + 255) / 256, 256, 0, stream>>>(ep, flag, endp, csr, E);

    // t_emb table: table = G @ Wt2.T + bt2 + b1   (1000 rows, fp32)
    dim3 gemm_grid_t((NT + 127) / 128, 2);
    gemm128_v3<<<gemm_grid_t, 256, 0, stream>>>(G, WTt2, bt2, b1, table, NT);

    int mfma_blocks = (N + 127) / 128;
    // xwh = bf16( dinv * (z @ W1.T) )
    gemm_mfma<1><<<mfma_blocks, 256, 0, stream>>>(z, W1, dinv, xwh, N);
    // acch = bf16( elu( dinv*(sum of xwh rows) + table[t] ) )
    gather_bf16<1><<<(N * 64 + 255) / 256, 256, 0, stream>>>(
        xwh, dinv, endp, deg, csr, table, t, nullptr, acch, N);
    // xwh = bf16( dinv * (acch @ W2.T) )
    gemm_mfma<0><<<mfma_blocks, 256, 0, stream>>>(acch, W2, dinv, xwh, N);
    // out = dinv*(sum of xwh rows) + b2   (fp32)
    gather_bf16<0><<<(N * 64 + 255) / 256, 256, 0, stream>>>(
        xwh, dinv, endp, deg, csr, nullptr, nullptr, b2, out, N);
}

// Round 8
// 171.850 us; speedup vs baseline: 2.6419x; 1.1800x over previous
//
#include <hip/hip_runtime.h>
#include <hip/hip_bf16.h>
#include <math.h>

#define D 128
#define ELLW 64

typedef __attribute__((ext_vector_type(8))) short short8v;
typedef __attribute__((ext_vector_type(4))) float f32x4;

__device__ __forceinline__ float gelu_exact(float x) {
    return 0.5f * x * (1.0f + erff(x * 0.70710678118654752440f));
}
__device__ __forceinline__ float elu1(float x) {
    return x > 0.f ? x : expm1f(x);
}
__device__ __forceinline__ unsigned short f2bf(float f) {   // RNE fp32->bf16 bits
    unsigned int u = __float_as_uint(f);
    u += 0x7fffu + ((u >> 16) & 1u);
    return (unsigned short)(u >> 16);
}
__device__ __forceinline__ float bflo(unsigned int u) {     // low bf16 of packed pair
    return __uint_as_float(u << 16);
}
__device__ __forceinline__ float bfhi(unsigned int u) {     // high bf16 of packed pair
    return __uint_as_float(u & 0xffff0000u);
}

// ---------------------------------------------------------------------------
// Fused prep:
//   idx in [0,N)                : deg[idx] = 0
//   idx in [N, N+16384)         : WTt2 transpose (fp32, table GEMM)
//   idx in [.., +NT*128)        : gelu table G
//   idx in [.., +16384)         : W1 -> bf16
//   idx in [.., +16384)         : W2 -> bf16
//   block 0 additionally detects int64-vs-int32 edge layout.
__global__ void prep_kernel(const int* __restrict__ ep, int* __restrict__ flag,
                            int* __restrict__ deg,
                            const float* __restrict__ Wt2, float* __restrict__ WT,
                            const float* __restrict__ wt1, const float* __restrict__ bt1,
                            float* __restrict__ G,
                            const float* __restrict__ W1, unsigned short* __restrict__ W1h,
                            const float* __restrict__ W2, unsigned short* __restrict__ W2h,
                            int n, int nt) {
    if (blockIdx.x == 0) {
        __shared__ int any;
        if (threadIdx.x == 0) any = 0;
        __syncthreads();
        for (int i = threadIdx.x; i < 2000; i += 256) {
            if (ep[2 * i + 1] != 0) any = 1;   // benign race
        }
        __syncthreads();
        if (threadIdx.x == 0) flag[0] = any ? 0 : 1;
    }
    int idx = blockIdx.x * blockDim.x + threadIdx.x;
    if (idx < n) { deg[idx] = 0; return; }
    idx -= n;
    if (idx < 16384) {
        int j = idx >> 7, k = idx & 127;
        WT[k * 128 + j] = Wt2[idx];
        return;
    }
    idx -= 16384;
    if (idx < nt * D) {
        int v = idx >> 7, k = idx & 127;
        G[idx] = gelu_exact(fmaf((float)v, wt1[k], bt1[k]));
        return;
    }
    idx -= nt * D;
    if (idx < 16384) { W1h[idx] = f2bf(W1[idx]); return; }
    idx -= 16384;
    if (idx < 16384) { W2h[idx] = f2bf(W2[idx]); }
}

// ---------------------------------------------------------------------------
// Single-pass ELL build: rank = old count; ell[c*ELLW + rank] = src row.
__global__ void fill_ell_kernel(const int* __restrict__ ep, const int* __restrict__ flag,
                                int* __restrict__ deg, int* __restrict__ ell, int E) {
    int e = blockIdx.x * blockDim.x + threadIdx.x;
    if (e >= E) return;
    int mode = flag[0];
    int r = mode ? ep[2 * e] : ep[e];
    int c = mode ? ep[2 * (E + e)] : ep[E + e];
    int rank = atomicAdd(&deg[c], 1);
    if (rank < ELLW) ell[(size_t)c * ELLW + rank] = r;
}

// ---------------------------------------------------------------------------
// fp32 GEMM (table path only, 1000 rows): out = A @ WT + bias + bias2
__global__ __launch_bounds__(256) void gemm128_v3(
    const float* __restrict__ Ain,
    const float* __restrict__ WT,
    const float* __restrict__ bias, const float* __restrict__ bias2,
    float* __restrict__ out, int n) {
    __shared__ float Wsh[128][68];
    const int tid = threadIdx.x;
    const int r0 = blockIdx.x * 128;
    const int jb = blockIdx.y * 64;

    #pragma unroll
    for (int rep = 0; rep < 8; ++rep) {
        int flat = rep * 256 + tid;
        int k = flat >> 4;
        int jj = (flat & 15) * 4;
        *(float4*)&Wsh[k][jj] = *(const float4*)(WT + k * D + jb + jj);
    }
    __syncthreads();

    const int tx = tid & 7, ty = tid >> 3;
    const int rbase = r0 + ty * 4;
    const int jcol = tx * 8;

    float acc[4][8];
    #pragma unroll
    for (int i = 0; i < 4; ++i)
        #pragma unroll
        for (int j = 0; j < 8; ++j) acc[i][j] = 0.f;

    #pragma unroll 2
    for (int k0 = 0; k0 < 128; k0 += 4) {
        float4 a[4];
        #pragma unroll
        for (int i = 0; i < 4; ++i) {
            int rr = rbase + i;
            a[i] = (rr < n) ? *(const float4*)(Ain + (size_t)rr * D + k0)
                            : make_float4(0.f, 0.f, 0.f, 0.f);
        }
        float4 wv[4][2];
        #pragma unroll
        for (int kk = 0; kk < 4; ++kk) {
            wv[kk][0] = *(const float4*)&Wsh[k0 + kk][jcol];
            wv[kk][1] = *(const float4*)&Wsh[k0 + kk][jcol + 4];
        }
        #pragma unroll
        for (int i = 0; i < 4; ++i) {
            float av[4] = {a[i].x, a[i].y, a[i].z, a[i].w};
            #pragma unroll
            for (int kk = 0; kk < 4; ++kk) {
                acc[i][0] = fmaf(av[kk], wv[kk][0].x, acc[i][0]);
                acc[i][1] = fmaf(av[kk], wv[kk][0].y, acc[i][1]);
                acc[i][2] = fmaf(av[kk], wv[kk][0].z, acc[i][2]);
                acc[i][3] = fmaf(av[kk], wv[kk][0].w, acc[i][3]);
                acc[i][4] = fmaf(av[kk], wv[kk][1].x, acc[i][4]);
                acc[i][5] = fmaf(av[kk], wv[kk][1].y, acc[i][5]);
                acc[i][6] = fmaf(av[kk], wv[kk][1].z, acc[i][6]);
                acc[i][7] = fmaf(av[kk], wv[kk][1].w, acc[i][7]);
            }
        }
    }

    float4 ba = *(const float4*)(bias + jb + jcol);
    float4 bb = *(const float4*)(bias2 + jb + jcol);
    float4 badd0 = make_float4(ba.x + bb.x, ba.y + bb.y, ba.z + bb.z, ba.w + bb.w);
    ba = *(const float4*)(bias + jb + jcol + 4);
    bb = *(const float4*)(bias2 + jb + jcol + 4);
    float4 badd1 = make_float4(ba.x + bb.x, ba.y + bb.y, ba.z + bb.z, ba.w + bb.w);
    #pragma unroll
    for (int i = 0; i < 4; ++i) {
        int rr = rbase + i;
        if (rr < n) {
            float4 o0, o1;
            o0.x = acc[i][0] + badd0.x; o0.y = acc[i][1] + badd0.y;
            o0.z = acc[i][2] + badd0.z; o0.w = acc[i][3] + badd0.w;
            o1.x = acc[i][4] + badd1.x; o1.y = acc[i][5] + badd1.y;
            o1.z = acc[i][6] + badd1.z; o1.w = acc[i][7] + badd1.w;
            *(float4*)(out + (size_t)rr * D + jb + jcol) = o0;
            *(float4*)(out + (size_t)rr * D + jb + jcol + 4) = o1;
        }
    }
}

// ---------------------------------------------------------------------------
// bf16 MFMA GEMM: outh[r][j] = bf16( dinv[r] * sum_k A[r][k] * W[j][k] )
// Swapped operands: D^T = W · A^T (mfma 16x16x32 bf16). W pre-converted bf16
// in global; fragments loaded directly (L2 broadcast) — no staging barrier.
// LDS used only for the store-transpose epilogue. dinv computed from deg.
template <int SRCF32>
__global__ __launch_bounds__(256) void gemm_mfma(
    const void* __restrict__ Ain,              // fp32 or bf16 [n][128]
    const unsigned short* __restrict__ Wh,     // bf16 [128][128] row-major (j,k)
    const int* __restrict__ deg,
    unsigned short* __restrict__ outh,         // bf16 [n][128]
    int n) {
    __shared__ unsigned short eb_all[4][32][136];
    const int tid = threadIdx.x;
    const int w   = tid >> 6;
    const int l   = tid & 63;
    const int l15 = l & 15;
    const int l4  = l >> 4;

    const int rb = blockIdx.x * 128 + w * 32;

    f32x4 acc[8][2];
    #pragma unroll
    for (int jt = 0; jt < 8; ++jt)
        #pragma unroll
        for (int rt = 0; rt < 2; ++rt)
            acc[jt][rt] = (f32x4){0.f, 0.f, 0.f, 0.f};

    #pragma unroll
    for (int ks = 0; ks < 4; ++ks) {
        const int kk = ks * 32 + l4 * 8;     // this lane's k base
        short8v bfrag[2];
        #pragma unroll
        for (int rt = 0; rt < 2; ++rt) {
            int r = rb + rt * 16 + l15;
            if (SRCF32) {
                const float* af = (const float*)Ain + (size_t)r * D + kk;
                float4 x0, x1;
                if (r < n) { x0 = *(const float4*)af; x1 = *(const float4*)(af + 4); }
                else       { x0 = make_float4(0,0,0,0); x1 = x0; }
                union { short8v v; unsigned short u[8]; } cv;
                cv.u[0] = f2bf(x0.x); cv.u[1] = f2bf(x0.y);
                cv.u[2] = f2bf(x0.z); cv.u[3] = f2bf(x0.w);
                cv.u[4] = f2bf(x1.x); cv.u[5] = f2bf(x1.y);
                cv.u[6] = f2bf(x1.z); cv.u[7] = f2bf(x1.w);
                bfrag[rt] = cv.v;
            } else {
                const unsigned short* ah = (const unsigned short*)Ain + (size_t)r * D + kk;
                if (r < n) bfrag[rt] = *(const short8v*)ah;
                else {
                    union { short8v v; unsigned short u[8]; } z0;
                    #pragma unroll
                    for (int q = 0; q < 8; ++q) z0.u[q] = 0;
                    bfrag[rt] = z0.v;
                }
            }
        }
        #pragma unroll
        for (int jt = 0; jt < 8; ++jt) {
            short8v afrag = *(const short8v*)(Wh + (size_t)(jt * 16 + l15) * D + kk);
            acc[jt][0] = __builtin_amdgcn_mfma_f32_16x16x32_bf16(afrag, bfrag[0], acc[jt][0], 0, 0, 0);
            acc[jt][1] = __builtin_amdgcn_mfma_f32_16x16x32_bf16(afrag, bfrag[1], acc[jt][1], 0, 0, 0);
        }
    }

    // epilogue: dinv scale, bf16, transpose via LDS, coalesced store
    int r0i = rb + l15, r1i = rb + 16 + l15;
    float dv0 = (r0i < n) ? rsqrtf((float)(deg[r0i] + 1)) : 0.f;
    float dv1 = (r1i < n) ? rsqrtf((float)(deg[r1i] + 1)) : 0.f;

    unsigned short* eb = &eb_all[w][0][0];
    #pragma unroll
    for (int jt = 0; jt < 8; ++jt) {
        #pragma unroll
        for (int rt = 0; rt < 2; ++rt) {
            int lr = rt * 16 + l15;
            float s = rt ? dv1 : dv0;
            f32x4 a = acc[jt][rt];
            unsigned int p0 = (unsigned int)f2bf(a[0] * s) | ((unsigned int)f2bf(a[1] * s) << 16);
            unsigned int p1 = (unsigned int)f2bf(a[2] * s) | ((unsigned int)f2bf(a[3] * s) << 16);
            int col = jt * 16 + l4 * 4;
            *(unsigned int*)(eb + lr * 136 + col)     = p0;
            *(unsigned int*)(eb + lr * 136 + col + 2) = p1;
        }
    }
    __syncthreads();
    #pragma unroll
    for (int rep = 0; rep < 8; ++rep) {
        int lr = rep * 4 + l4;
        int c8 = l15 * 8;
        int row = rb + lr;
        if (row < n)
            *(uint4*)(outh + (size_t)row * D + c8) = *(const uint4*)(eb + lr * 136 + c8);
    }
}

// ---------------------------------------------------------------------------
// Gather-aggregation over pre-scaled bf16 rows xh (already scaled by dinv[src]).
//   sum = xh[i] + sum_{r in ell-row(i)} xh[r];  val = dinv(i)*sum
// EPI 0: out fp32 = val + bias             (final output + b2)
// EPI 1: out bf16 = elu(val + table[t[i]]) (h1 path, feeds GEMM2)
template <int EPI>
__global__ __launch_bounds__(256) void gather_bf16(
    const unsigned short* __restrict__ xh, const int* __restrict__ deg,
    const int* __restrict__ ell,
    const float* __restrict__ table, const int* __restrict__ tvec,
    const float* __restrict__ bias,
    void* __restrict__ dst, int n) {
    int wid = (blockIdx.x * 256 + threadIdx.x) >> 6;
    if (wid >= n) return;
    int lane = threadIdx.x & 63;
    const int lo = lane * 2;

    int dgr = deg[wid];
    float di = rsqrtf((float)(dgr + 1));
    int dg = dgr > ELLW ? ELLW : dgr;
    const int* row = ell + (size_t)wid * ELLW;

    float2 ep;
    if (EPI == 0) {
        ep = *(const float2*)(bias + lo);
    } else {
        int tv = tvec[wid];
        ep = *(const float2*)(table + (size_t)tv * D + lo);
    }

    unsigned int sv = *(const unsigned int*)(xh + (size_t)wid * D + lo);
    float sx = bflo(sv), sy = bfhi(sv);
    int e = 0;
    for (; e + 8 <= dg; e += 8) {
        int r0 = row[e],     r1 = row[e + 1], r2 = row[e + 2], r3 = row[e + 3];
        int r4 = row[e + 4], r5 = row[e + 5], r6 = row[e + 6], r7 = row[e + 7];
        unsigned int u0 = *(const unsigned int*)(xh + (size_t)r0 * D + lo);
        unsigned int u1 = *(const unsigned int*)(xh + (size_t)r1 * D + lo);
        unsigned int u2 = *(const unsigned int*)(xh + (size_t)r2 * D + lo);
        unsigned int u3 = *(const unsigned int*)(xh + (size_t)r3 * D + lo);
        unsigned int u4 = *(const unsigned int*)(xh + (size_t)r4 * D + lo);
        unsigned int u5 = *(const unsigned int*)(xh + (size_t)r5 * D + lo);
        unsigned int u6 = *(const unsigned int*)(xh + (size_t)r6 * D + lo);
        unsigned int u7 = *(const unsigned int*)(xh + (size_t)r7 * D + lo);
        sx += ((bflo(u0) + bflo(u1)) + (bflo(u2) + bflo(u3)))
            + ((bflo(u4) + bflo(u5)) + (bflo(u6) + bflo(u7)));
        sy += ((bfhi(u0) + bfhi(u1)) + (bfhi(u2) + bfhi(u3)))
            + ((bfhi(u4) + bfhi(u5)) + (bfhi(u6) + bfhi(u7)));
    }
    for (; e < dg; ++e) {
        int r0 = row[e];
        unsigned int u0 = *(const unsigned int*)(xh + (size_t)r0 * D + lo);
        sx += bflo(u0);
        sy += bfhi(u0);
    }

    float ox = di * sx + ep.x;
    float oy = di * sy + ep.y;
    if (EPI == 0) {
        *(float2*)((float*)dst + (size_t)wid * D + lo) = make_float2(ox, oy);
    } else {
        ox = elu1(ox); oy = elu1(oy);
        unsigned int p = (unsigned int)f2bf(ox) | ((unsigned int)f2bf(oy) << 16);
        *(unsigned int*)((unsigned short*)dst + (size_t)wid * D + lo) = p;
    }
}

// ---------------------------------------------------------------------------
extern "C" void kernel_launch(void* const* d_in, const int* in_sizes, int n_in,
                              void* d_out, int out_size, void* d_ws, size_t ws_size,
                              hipStream_t stream) {
    const float* z   = (const float*)d_in[0];
    const int*   ep  = (const int*)d_in[1];
    const int*   t   = (const int*)d_in[2];
    const float* Wt1 = (const float*)d_in[3];
    const float* bt1 = (const float*)d_in[4];
    const float* Wt2 = (const float*)d_in[5];
    const float* bt2 = (const float*)d_in[6];
    const float* W1  = (const float*)d_in[7];
    const float* b1  = (const float*)d_in[8];
    const float* W2  = (const float*)d_in[9];
    const float* b2  = (const float*)d_in[10];
    float* out = (float*)d_out;

    const int N = in_sizes[0] / D;     // 50000
    const int E = in_sizes[1] / 2;     // 640000
    const int NT = 1000;               // distinct t values

    size_t off = 0;
    auto carve = [&](size_t nbytes) -> void* {
        void* p = (void*)((char*)d_ws + off);
        off += (nbytes + 255) & ~(size_t)255;
        return p;
    };
    int*   flag   = (int*)carve(256);
    int*   deg    = (int*)carve((size_t)N * 4);
    int*   ell    = (int*)carve((size_t)N * ELLW * 4);
    float* WTt2   = (float*)carve((size_t)16384 * 4);
    float* G      = (float*)carve((size_t)NT * D * 4);
    float* table  = (float*)carve((size_t)NT * D * 4);
    unsigned short* W1h  = (unsigned short*)carve((size_t)16384 * 2);
    unsigned short* W2h  = (unsigned short*)carve((size_t)16384 * 2);
    unsigned short* xwh  = (unsigned short*)carve((size_t)N * D * 2);
    unsigned short* acch = (unsigned short*)carve((size_t)N * D * 2);
    (void)ws_size; (void)n_in; (void)out_size;

    int prep_total = N + 16384 + NT * D + 16384 + 16384;
    prep_kernel<<<(prep_total + 255) / 256, 256, 0, stream>>>(
        ep, flag, deg, Wt2, WTt2, Wt1, bt1, G, W1, W1h, W2, W2h, N, NT);
    fill_ell_kernel<<<(E + 255) / 256, 256, 0, stream>>>(ep, flag, deg, ell, E);

    // t_emb table: table = G @ Wt2.T + bt2 + b1   (1000 rows, fp32)
    dim3 gemm_grid_t((NT + 127) / 128, 2);
    gemm128_v3<<<gemm_grid_t, 256, 0, stream>>>(G, WTt2, bt2, b1, table, NT);

    int mfma_blocks = (N + 127) / 128;
    // xwh = bf16( dinv * (z @ W1.T) )
    gemm_mfma<1><<<mfma_blocks, 256, 0, stream>>>(z, W1h, deg, xwh, N);
    // acch = bf16( elu( dinv*(sum of xwh rows) + table[t] ) )
    gather_bf16<1><<<(N * 64 + 255) / 256, 256, 0, stream>>>(
        xwh, deg, ell, table, t, nullptr, acch, N);
    // xwh = bf16( dinv * (acch @ W2.T) )
    gemm_mfma<0><<<mfma_blocks, 256, 0, stream>>>(acch, W2h, deg, xwh, N);
    // out = dinv*(sum of xwh rows) + b2   (fp32)
    gather_bf16<0><<<(N * 64 + 255) / 256, 256, 0, stream>>>(
        xwh, deg, ell, nullptr, nullptr, b2, out, N);
}